// Round 3
// baseline (1389.564 us; speedup 1.0000x reference)
//
#include <hip/hip_runtime.h>
#include <hip/hip_bf16.h>
#include <math.h>

#define FEAT 1040
#define NHEAD 8
#define DHEAD 130
#define NLAYER 3
#define NGRAPH 64
#define NEG_SLOPE 0.2f
#define BN_EPS 1e-5f
#define KP 1056   // FEAT padded to multiple of 32 (K of GEMM)
#define NP 1152   // FEAT padded to multiple of 128; cols 1040..1055 = wa_src/wa_dst
#define CH 512    // edges per LDS chunk in fused aggregate

typedef float floatx4 __attribute__((ext_vector_type(4)));
typedef short shortx8 __attribute__((ext_vector_type(8)));

__device__ __forceinline__ short f2bf(float f) {
    unsigned u = __float_as_uint(f);
    u += 0x7fff + ((u >> 16) & 1);   // round-to-nearest-even
    return (short)(u >> 16);
}
__device__ __forceinline__ float bf2f(short b) {
    return __uint_as_float(((unsigned)(unsigned short)b) << 16);
}

__device__ __forceinline__ void async16(const void* g, void* l) {
    __builtin_amdgcn_global_load_lds(
        (const __attribute__((address_space(1))) unsigned int*)g,
        (__attribute__((address_space(3))) unsigned int*)l, 16, 0, 0);
}

// ---------------- bf16 MFMA GEMM, double-buffered + XCD swizzle ----------------
__global__ __launch_bounds__(256) void gemm_mfma(const short* __restrict__ A,
                                                 const short* __restrict__ Bt,
                                                 short* __restrict__ xh_bf,
                                                 float* __restrict__ asrc,
                                                 float* __restrict__ adst,
                                                 int M, int MT) {
    const int lid = blockIdx.x;
    const int g = lid / 72, r = lid % 72;
    const int bmi = g * 8 + (r & 7);
    const int bni = r >> 3;
    if (bmi >= MT) return;
    const int bm = bmi * 128;
    const int bn = bni * 128;

    __shared__ short As[2][4096];
    __shared__ short Bs[2][4096];
    const int tid = threadIdx.x;
    const int lane = tid & 63;
    const int w = tid >> 6;
    const int wm = (w & 1) * 64;
    const int wn = (w >> 1) * 64;

    const int tt0 = tid, tt1 = 256 + tid;
    const int row0 = ((tt0 >> 6) << 4) | (tt0 & 15);
    const int col0 = ((tt0 >> 4) & 3) * 8;
    const int row1 = ((tt1 >> 6) << 4) | (tt1 & 15);
    const int col1 = ((tt1 >> 4) & 3) * 8;

    const short* gA0 = A + (size_t)(bm + row0) * KP + col0;
    const short* gA1 = A + (size_t)(bm + row1) * KP + col1;
    const short* gB0 = Bt + (size_t)(bn + row0) * KP + col0;
    const short* gB1 = Bt + (size_t)(bn + row1) * KP + col1;

    const int fr = lane & 15;
    const int kq = lane >> 4;

    floatx4 acc[4][4];
#pragma unroll
    for (int i = 0; i < 4; i++)
#pragma unroll
        for (int j = 0; j < 4; j++) acc[i][j] = (floatx4){0.f, 0.f, 0.f, 0.f};

    async16(gA0, &As[0][tt0 * 8]);
    async16(gA1, &As[0][tt1 * 8]);
    async16(gB0, &Bs[0][tt0 * 8]);
    async16(gB1, &Bs[0][tt1 * 8]);
    __syncthreads();

    int cur = 0;
    for (int k0 = 0; k0 < KP; k0 += 32) {
        const int nxt = cur ^ 1;
        const int k1 = k0 + 32;
        if (k1 < KP) {
            async16(gA0 + k1, &As[nxt][tt0 * 8]);
            async16(gA1 + k1, &As[nxt][tt1 * 8]);
            async16(gB0 + k1, &Bs[nxt][tt0 * 8]);
            async16(gB1 + k1, &Bs[nxt][tt1 * 8]);
        }
        shortx8 af[4], bfr[4];
#pragma unroll
        for (int i = 0; i < 4; i++) {
            af[i]  = *(const shortx8*)&As[cur][((wm >> 4) + i) * 512 + kq * 128 + fr * 8];
            bfr[i] = *(const shortx8*)&Bs[cur][((wn >> 4) + i) * 512 + kq * 128 + fr * 8];
        }
#pragma unroll
        for (int i = 0; i < 4; i++)
#pragma unroll
            for (int j = 0; j < 4; j++)
                acc[i][j] = __builtin_amdgcn_mfma_f32_16x16x32_bf16(af[i], bfr[j], acc[i][j], 0, 0, 0);
        __syncthreads();
        cur = nxt;
    }

    const int rbase = (lane >> 4) * 4;
    const int ccol = lane & 15;
#pragma unroll
    for (int j = 0; j < 4; j++) {
        int colbase = bn + wn + j * 16;
        if (colbase < FEAT) {
            int col = colbase + ccol;
#pragma unroll
            for (int i = 0; i < 4; i++)
#pragma unroll
                for (int r2 = 0; r2 < 4; r2++) {
                    int row = bm + wm + i * 16 + rbase + r2;
                    if (row < M) xh_bf[(size_t)row * FEAT + col] = f2bf(acc[i][j][r2]);
                }
        } else if (colbase == FEAT) {
            int c = ccol;
            float* tgt = (c < 8) ? asrc : adst;
            int h = c & 7;
#pragma unroll
            for (int i = 0; i < 4; i++)
#pragma unroll
                for (int r2 = 0; r2 < 4; r2++) {
                    int row = bm + wm + i * 16 + rbase + r2;
                    if (row < M) tgt[(size_t)row * NHEAD + h] = acc[i][j][r2];
                }
        }
    }
}

// ---------------- conversions / padding ----------------
__global__ void conv_x_bf(const float* __restrict__ x, short* __restrict__ out, int N) {
    int idx = blockIdx.x * 256 + threadIdx.x;   // index of 4-elem group
    int total = N * (FEAT / 4);
    if (idx >= total) return;
    int r = idx / (FEAT / 4), c4 = idx - r * (FEAT / 4);
    float4 v = *(const float4*)(x + (size_t)r * FEAT + c4 * 4);
    ushort4 o;
    o.x = (unsigned short)f2bf(v.x);
    o.y = (unsigned short)f2bf(v.y);
    o.z = (unsigned short)f2bf(v.z);
    o.w = (unsigned short)f2bf(v.w);
    *(ushort4*)(out + (size_t)r * KP + c4 * 4) = o;
}

__global__ void pad_bf(short* __restrict__ buf, int Mvalid) {
    int r = blockIdx.x;
    short* row = buf + (size_t)r * KP;
    if (r < Mvalid) {
        if (threadIdx.x < KP - FEAT) row[FEAT + threadIdx.x] = 0;
    } else {
        for (int c = threadIdx.x; c < KP; c += 64) row[c] = 0;
    }
}

__global__ void transpose_w(const float* __restrict__ Wl, short* __restrict__ Bt) {
    __shared__ float t[32][33];
    int kb = blockIdx.x * 32, nb = blockIdx.y * 32;
    int tx = threadIdx.x & 31, ty = threadIdx.x >> 5;
#pragma unroll
    for (int i = 0; i < 4; i++) {
        int k = kb + ty + i * 8, n = nb + tx;
        t[ty + i * 8][tx] = (k < FEAT && n < FEAT) ? Wl[(size_t)k * FEAT + n] : 0.f;
    }
    __syncthreads();
#pragma unroll
    for (int i = 0; i < 4; i++) {
        int n = nb + ty + i * 8, k = kb + tx;
        if (n < FEAT && k < FEAT) Bt[(size_t)n * KP + k] = f2bf(t[tx][ty + i * 8]);
    }
}

__global__ void wa_kernel(const float* __restrict__ W, const float* __restrict__ a_s,
                          const float* __restrict__ a_d, short* __restrict__ Bt3) {
    int t = blockIdx.x * 256 + threadIdx.x;
    if (t >= NLAYER * FEAT * NHEAD) return;
    int h = t & 7;
    int f = (t >> 3) % FEAT;
    int l = t / (FEAT * NHEAD);
    const float* wrow = W + (((size_t)l * FEAT + f) * NHEAD + h) * DHEAD;
    const float* as = a_s + ((size_t)l * NHEAD + h) * DHEAD;
    const float* ad = a_d + ((size_t)l * NHEAD + h) * DHEAD;
    float ws = 0.f, wd = 0.f;
    for (int d = 0; d < DHEAD; d++) {
        float wv = wrow[d];
        ws += wv * as[d];
        wd += wv * ad[d];
    }
    short* base = Bt3 + (size_t)l * NP * KP;
    base[(size_t)(FEAT + h) * KP + f] = f2bf(ws);
    base[(size_t)(FEAT + 8 + h) * KP + f] = f2bf(wd);
}

// ---------------- graph preprocessing ----------------
__global__ void build_edges(const int* __restrict__ ei, int E, int N,
                            int* __restrict__ src2, int* __restrict__ dst2,
                            int* __restrict__ deg) {
    int e = blockIdx.x * 256 + threadIdx.x;
    int E2 = E + N;
    if (e >= E2) return;
    int s, d;
    if (e < E) { s = ei[e]; d = ei[E + e]; }
    else       { s = e - E; d = e - E; }
    src2[e] = s;
    dst2[e] = d;
    atomicAdd(&deg[d], 1);
}

__global__ void scan_kernel(const int* __restrict__ deg, int* __restrict__ off,
                            int* __restrict__ cursor, int N) {
    __shared__ int wsum[16];
    __shared__ int carry_s;
    int tid = threadIdx.x;
    int lane = tid & 63, wid = tid >> 6;
    if (tid == 0) carry_s = 0;
    __syncthreads();
    for (int base = 0; base < N; base += 1024) {
        int i = base + tid;
        int v = (i < N) ? deg[i] : 0;
        int incl = v;
#pragma unroll
        for (int o = 1; o < 64; o <<= 1) {
            int u = __shfl_up(incl, o);
            if (lane >= o) incl += u;
        }
        if (lane == 63) wsum[wid] = incl;
        __syncthreads();
        if (wid == 0) {
            int wv = (lane < 16) ? wsum[lane] : 0;
            int wincl = wv;
#pragma unroll
            for (int o = 1; o < 16; o <<= 1) {
                int u = __shfl_up(wincl, o);
                if (lane >= o) wincl += u;
            }
            if (lane < 16) wsum[lane] = wincl - wv;
        }
        __syncthreads();
        int excl = carry_s + wsum[wid] + incl - v;
        if (i < N) { off[i] = excl; cursor[i] = excl; }
        int tot = 0;
        if (tid == 1023) tot = wsum[15] + incl;
        __syncthreads();
        if (tid == 1023) carry_s += tot;
        __syncthreads();
    }
    if (threadIdx.x == 0) off[N] = carry_s;
}

__global__ void scatter_k(const int* __restrict__ src2, const int* __restrict__ dst2,
                          int* __restrict__ cursor, int* __restrict__ ssrc, int E2) {
    int e = blockIdx.x * 256 + threadIdx.x;
    if (e >= E2) return;
    int d = dst2[e];
    int pos = atomicAdd(&cursor[d], 1);
    ssrc[pos] = src2[e];
}

__global__ void gstart_k(const int* __restrict__ batch, int* __restrict__ gstart, int N) {
    int n = blockIdx.x * 256 + threadIdx.x;
    if (n >= N) return;
    int b = batch[n];
    if (n == 0) {
        for (int g = 0; g <= b; g++) gstart[g] = 0;
    } else {
        int pb = batch[n - 1];
        for (int g = pb + 1; g <= b; g++) gstart[g] = n;
    }
    if (n == N - 1) {
        for (int g = b + 1; g <= NGRAPH; g++) gstart[g] = N;
    }
}

// ---- fused: leaky-relu + segment softmax + aggregation + BN + ReLU ----------
// Block = 1 dst node, 320 threads (5 waves). Phase 1: per-head max over incoming
// edges (threads strided over (edge,head), h = t&7 fixed). Phase 2 (chunked by
// CH edges): exp into LDS p_s + per-head partial sums, then 8-B gathers of
// xh_bf[src] weighted by p_s. Denominator folded at the end from LDS.
__global__ __launch_bounds__(320) void aggregate(
    const short* __restrict__ xh_bf,
    const float* __restrict__ asrc, const float* __restrict__ adst,
    const int* __restrict__ off, const int* __restrict__ ssrc,
    const float* __restrict__ prev_f,     // fp32 residual (layer 1: x) or null
    const short* __restrict__ prev_bf,    // bf16 residual (layer 2: hA_bf) or null
    const float* __restrict__ b_att, const float* __restrict__ gamma,
    const float* __restrict__ beta, const float* __restrict__ mean,
    const float* __restrict__ var,
    short* __restrict__ hout_bf, int N) {
    const int n = blockIdx.x;
    const int t = threadIdx.x;
    const int lane = t & 63;
    const int wv = t >> 6;
    const int h8 = t & 7;

    __shared__ float p_s[CH * NHEAD];   // 16 KB
    __shared__ float red[5 * NHEAD];
    __shared__ float m_sh[NHEAD];
    __shared__ float dinv_sh[NHEAD];

    const int s = off[n], e = off[n + 1];
    const int deg = e - s;
    const float ad = adst[(size_t)n * NHEAD + h8];

    // ---- phase 1: per-head max (all 320 threads) ----
    float mt = -INFINITY;
    for (int jh = t; jh < deg * NHEAD; jh += 320) {
        int j = jh >> 3;
        float v = asrc[(size_t)ssrc[s + j] * NHEAD + h8] + ad;
        v = (v > 0.f) ? v : NEG_SLOPE * v;
        mt = fmaxf(mt, v);
    }
    mt = fmaxf(mt, __shfl_xor(mt, 8));
    mt = fmaxf(mt, __shfl_xor(mt, 16));
    mt = fmaxf(mt, __shfl_xor(mt, 32));
    if (lane < 8) red[wv * 8 + lane] = mt;
    __syncthreads();
    if (t < 8) {
        float m = red[t];
#pragma unroll
        for (int w2 = 1; w2 < 5; w2++) m = fmaxf(m, red[w2 * 8 + t]);
        m_sh[t] = m;
    }
    __syncthreads();
    const float mh = m_sh[h8];

    // ---- phase 2: chunked exp -> LDS, gather-accumulate ----
    const int f0 = t * 4;                      // valid when t < 260
    const int hA = f0 / DHEAD;
    const int hB = (f0 + 3) / DHEAD;
    const int sp = hB * DHEAD - f0;            // feats i<sp use head hA
    float acc[4] = {0.f, 0.f, 0.f, 0.f};
    float psum = 0.f;

    for (int c0 = 0; c0 < deg; c0 += CH) {
        const int cnt = min(CH, deg - c0);
        for (int jh = t; jh < cnt * NHEAD; jh += 320) {
            int j = jh >> 3;
            float v = asrc[(size_t)ssrc[s + c0 + j] * NHEAD + h8] + ad;
            v = (v > 0.f) ? v : NEG_SLOPE * v;
            float pe = __expf(v - mh);
            p_s[j * NHEAD + h8] = pe;
            psum += pe;
        }
        __syncthreads();
        if (t < 260) {
            int j = 0;
            for (; j + 8 <= cnt; j += 8) {
                int sj[8];
                ushort4 v[8];
#pragma unroll
                for (int u = 0; u < 8; u++) sj[u] = ssrc[s + c0 + j + u];
#pragma unroll
                for (int u = 0; u < 8; u++)
                    v[u] = *(const ushort4*)(xh_bf + (size_t)sj[u] * FEAT + f0);
#pragma unroll
                for (int u = 0; u < 8; u++) {
                    float pa = p_s[(j + u) * NHEAD + hA];
                    float pb = p_s[(j + u) * NHEAD + hB];
                    acc[0] += ((0 < sp) ? pa : pb) * bf2f((short)v[u].x);
                    acc[1] += ((1 < sp) ? pa : pb) * bf2f((short)v[u].y);
                    acc[2] += ((2 < sp) ? pa : pb) * bf2f((short)v[u].z);
                    acc[3] += ((3 < sp) ? pa : pb) * bf2f((short)v[u].w);
                }
            }
            for (; j + 4 <= cnt; j += 4) {
                int sj[4];
                ushort4 v[4];
#pragma unroll
                for (int u = 0; u < 4; u++) sj[u] = ssrc[s + c0 + j + u];
#pragma unroll
                for (int u = 0; u < 4; u++)
                    v[u] = *(const ushort4*)(xh_bf + (size_t)sj[u] * FEAT + f0);
#pragma unroll
                for (int u = 0; u < 4; u++) {
                    float pa = p_s[(j + u) * NHEAD + hA];
                    float pb = p_s[(j + u) * NHEAD + hB];
                    acc[0] += ((0 < sp) ? pa : pb) * bf2f((short)v[u].x);
                    acc[1] += ((1 < sp) ? pa : pb) * bf2f((short)v[u].y);
                    acc[2] += ((2 < sp) ? pa : pb) * bf2f((short)v[u].z);
                    acc[3] += ((3 < sp) ? pa : pb) * bf2f((short)v[u].w);
                }
            }
            for (; j < cnt; j++) {
                int sj = ssrc[s + c0 + j];
                ushort4 v = *(const ushort4*)(xh_bf + (size_t)sj * FEAT + f0);
                float pa = p_s[j * NHEAD + hA];
                float pb = p_s[j * NHEAD + hB];
                acc[0] += ((0 < sp) ? pa : pb) * bf2f((short)v.x);
                acc[1] += ((1 < sp) ? pa : pb) * bf2f((short)v.y);
                acc[2] += ((2 < sp) ? pa : pb) * bf2f((short)v.z);
                acc[3] += ((3 < sp) ? pa : pb) * bf2f((short)v.w);
            }
        }
        __syncthreads();   // protect p_s before next chunk overwrite
    }

    // ---- per-head denominator ----
    psum += __shfl_xor(psum, 8);
    psum += __shfl_xor(psum, 16);
    psum += __shfl_xor(psum, 32);
    if (lane < 8) red[wv * 8 + lane] = psum;
    __syncthreads();
    if (t < 8) {
        float ssum = red[t] + red[8 + t] + red[16 + t] + red[24 + t] + red[32 + t];
        dinv_sh[t] = 1.0f / ssum;
    }
    __syncthreads();

    if (t >= 260) return;
    float da = dinv_sh[hA];
    float db = dinv_sh[hB];
    acc[0] *= (0 < sp) ? da : db;
    acc[1] *= (1 < sp) ? da : db;
    acc[2] *= (2 < sp) ? da : db;
    acc[3] *= (3 < sp) ? da : db;

    float4 bv = *(const float4*)(b_att + f0);
    float4 gv = *(const float4*)(gamma + f0);
    float4 be = *(const float4*)(beta + f0);
    float4 mv = *(const float4*)(mean + f0);
    float4 vv = *(const float4*)(var + f0);
    float z[4] = {acc[0] + bv.x, acc[1] + bv.y, acc[2] + bv.z, acc[3] + bv.w};
    if (prev_f) {
        float4 pv = *(const float4*)(prev_f + (size_t)n * FEAT + f0);
        z[0] += pv.x; z[1] += pv.y; z[2] += pv.z; z[3] += pv.w;
    }
    if (prev_bf) {
        ushort4 pv = *(const ushort4*)(prev_bf + (size_t)n * KP + f0);
        z[0] += bf2f((short)pv.x); z[1] += bf2f((short)pv.y);
        z[2] += bf2f((short)pv.z); z[3] += bf2f((short)pv.w);
    }
    float g4[4] = {gv.x, gv.y, gv.z, gv.w};
    float b4[4] = {be.x, be.y, be.z, be.w};
    float m4[4] = {mv.x, mv.y, mv.z, mv.w};
    float v4[4] = {vv.x, vv.y, vv.z, vv.w};
    ushort4 o;
    unsigned short* op = (unsigned short*)&o;
#pragma unroll
    for (int i = 0; i < 4; i++) {
        float zz = (z[i] - m4[i]) * rsqrtf(v4[i] + BN_EPS) * g4[i] + b4[i];
        op[i] = (unsigned short)f2bf(fmaxf(zz, 0.f));
    }
    *(ushort4*)(hout_bf + (size_t)n * KP + f0) = o;
}

// ---------------- pooling over contiguous node ranges ----------------
__global__ __launch_bounds__(320) void pool_k(const short* __restrict__ h,
                                              const int* __restrict__ gstart,
                                              float* __restrict__ pooled) {
    int g = blockIdx.x;
    int t = threadIdx.x;
    if (t >= 260) return;
    int f0 = t * 4;
    int s = gstart[g], e = gstart[g + 1];
    float acc[4] = {0.f, 0.f, 0.f, 0.f};
    int n = s;
    for (; n + 4 <= e; n += 4) {
        ushort4 v0 = *(const ushort4*)(h + (size_t)n * KP + f0);
        ushort4 v1 = *(const ushort4*)(h + (size_t)(n + 1) * KP + f0);
        ushort4 v2 = *(const ushort4*)(h + (size_t)(n + 2) * KP + f0);
        ushort4 v3 = *(const ushort4*)(h + (size_t)(n + 3) * KP + f0);
        acc[0] += bf2f((short)v0.x) + bf2f((short)v1.x) + bf2f((short)v2.x) + bf2f((short)v3.x);
        acc[1] += bf2f((short)v0.y) + bf2f((short)v1.y) + bf2f((short)v2.y) + bf2f((short)v3.y);
        acc[2] += bf2f((short)v0.z) + bf2f((short)v1.z) + bf2f((short)v2.z) + bf2f((short)v3.z);
        acc[3] += bf2f((short)v0.w) + bf2f((short)v1.w) + bf2f((short)v2.w) + bf2f((short)v3.w);
    }
    for (; n < e; n++) {
        ushort4 v = *(const ushort4*)(h + (size_t)n * KP + f0);
        acc[0] += bf2f((short)v.x);
        acc[1] += bf2f((short)v.y);
        acc[2] += bf2f((short)v.z);
        acc[3] += bf2f((short)v.w);
    }
    *(float4*)(pooled + (size_t)g * FEAT + f0) = make_float4(acc[0], acc[1], acc[2], acc[3]);
}

__global__ void final_k(const float* __restrict__ pooled, const int* __restrict__ gstart,
                        const float* __restrict__ W_out, const float* __restrict__ b_out,
                        float* __restrict__ out) {
    int g = blockIdx.x >> 1, c = blockIdx.x & 1;
    int lane = threadIdx.x;  // 64
    float ssum = 0.f;
    for (int f = lane; f < FEAT; f += 64) ssum += pooled[(size_t)g * FEAT + f] * W_out[f * 2 + c];
#pragma unroll
    for (int o = 1; o < 64; o <<= 1) ssum += __shfl_xor(ssum, o);
    if (lane == 0) {
        float cnt = (float)(gstart[g + 1] - gstart[g]);
        float inv = 1.0f / fmaxf(cnt, 1.0f);
        out[g * 2 + c] = ssum * inv + b_out[c];
    }
}

// ---------------- launch ----------------
extern "C" void kernel_launch(void* const* d_in, const int* in_sizes, int n_in,
                              void* d_out, int out_size, void* d_ws, size_t ws_size,
                              hipStream_t stream) {
    const float* x       = (const float*)d_in[0];
    const int*   ei      = (const int*)d_in[1];
    const int*   batch   = (const int*)d_in[2];
    const float* W       = (const float*)d_in[3];
    const float* a_src   = (const float*)d_in[4];
    const float* a_dst   = (const float*)d_in[5];
    const float* b_att   = (const float*)d_in[6];
    const float* gamma   = (const float*)d_in[7];
    const float* beta    = (const float*)d_in[8];
    const float* r_mean  = (const float*)d_in[9];
    const float* r_var   = (const float*)d_in[10];
    const float* W_out   = (const float*)d_in[11];
    const float* b_out   = (const float*)d_in[12];
    float* out = (float*)d_out;

    const int N = in_sizes[0] / FEAT;
    const int E = in_sizes[1] / 2;
    const int E2 = E + N;
    const int MT = (N + 127) / 128;
    const int Mp = MT * 128;
    const int MTpad = ((MT + 7) / 8) * 8;

    char* w = (char*)d_ws;
    auto alloc = [&](size_t bytes) {
        void* pp = (void*)w;
        w += (bytes + 255) & ~(size_t)255;
        return pp;
    };
    short* xh_bf  = (short*)alloc((size_t)N * FEAT * 2);
    short* x_bf   = (short*)alloc((size_t)Mp * KP * 2);   // layer-0 A; reused as layer-3 h
    short* hA_bf  = (short*)alloc((size_t)Mp * KP * 2);
    short* hB_bf  = (short*)alloc((size_t)Mp * KP * 2);
    short* Bt3    = (short*)alloc((size_t)NLAYER * NP * KP * 2);
    float* asrc   = (float*)alloc((size_t)N * NHEAD * 4);
    float* adst   = (float*)alloc((size_t)N * NHEAD * 4);
    int*   src2   = (int*)alloc((size_t)E2 * 4);
    int*   dst2   = (int*)alloc((size_t)E2 * 4);
    int*   ssrc   = (int*)alloc((size_t)E2 * 4);
    int*   deg    = (int*)alloc((size_t)N * 4);
    int*   off    = (int*)alloc((size_t)(N + 1) * 4);
    int*   cursor = (int*)alloc((size_t)N * 4);
    int*   gstart = (int*)alloc((size_t)(NGRAPH + 1) * 4);
    float* pooled = (float*)alloc((size_t)NGRAPH * FEAT * 4);

    hipMemsetAsync(deg, 0, (size_t)N * 4, stream);
    hipMemsetAsync(Bt3, 0, (size_t)NLAYER * NP * KP * 2, stream);

    conv_x_bf<<<(N * (FEAT / 4) + 255) / 256, 256, 0, stream>>>(x, x_bf, N);
    pad_bf<<<Mp, 64, 0, stream>>>(x_bf, N);
    pad_bf<<<Mp, 64, 0, stream>>>(hA_bf, N);
    pad_bf<<<Mp, 64, 0, stream>>>(hB_bf, N);
    dim3 tgrid((FEAT + 31) / 32, (FEAT + 31) / 32);
    for (int l = 0; l < NLAYER; l++)
        transpose_w<<<tgrid, 256, 0, stream>>>(W + (size_t)l * FEAT * FEAT,
                                               Bt3 + (size_t)l * NP * KP);
    wa_kernel<<<(NLAYER * FEAT * NHEAD + 255) / 256, 256, 0, stream>>>(W, a_src, a_dst, Bt3);

    build_edges<<<(E2 + 255) / 256, 256, 0, stream>>>(ei, E, N, src2, dst2, deg);
    scan_kernel<<<1, 1024, 0, stream>>>(deg, off, cursor, N);
    scatter_k<<<(E2 + 255) / 256, 256, 0, stream>>>(src2, dst2, cursor, ssrc, E2);
    gstart_k<<<(N + 255) / 256, 256, 0, stream>>>(batch, gstart, N);

    const short* hin[NLAYER]     = {x_bf, hA_bf, hB_bf};
    const float* prevf[NLAYER]   = {nullptr, x, nullptr};
    const short* prevbf[NLAYER]  = {nullptr, nullptr, hA_bf};
    short* houtl[NLAYER]         = {hA_bf, hB_bf, x_bf};

    for (int l = 0; l < NLAYER; l++) {
        gemm_mfma<<<MTpad * 9, 256, 0, stream>>>(hin[l], Bt3 + (size_t)l * NP * KP,
                                                 xh_bf, asrc, adst, N, MT);
        aggregate<<<N, 320, 0, stream>>>(xh_bf, asrc, adst, off, ssrc, prevf[l], prevbf[l],
                                         b_att + l * FEAT, gamma + l * FEAT, beta + l * FEAT,
                                         r_mean + l * FEAT, r_var + l * FEAT,
                                         houtl[l], N);
    }

    pool_k<<<NGRAPH, 320, 0, stream>>>(x_bf, gstart, pooled);
    final_k<<<NGRAPH * 2, 64, 0, stream>>>(pooled, gstart, W_out, b_out, out);
}

// Round 4
// 1120.033 us; speedup vs baseline: 1.2406x; 1.2406x over previous
//
#include <hip/hip_runtime.h>
#include <hip/hip_bf16.h>
#include <math.h>

#define FEAT 1040
#define NHEAD 8
#define DHEAD 130
#define NLAYER 3
#define NGRAPH 64
#define NEG_SLOPE 0.2f
#define BN_EPS 1e-5f
#define KP 1056   // FEAT padded to multiple of 32 (K of GEMM)
#define NP 1152   // FEAT padded to multiple of 128; cols 1040..1055 = wa_src/wa_dst

typedef float floatx4 __attribute__((ext_vector_type(4)));
typedef short shortx8 __attribute__((ext_vector_type(8)));

__device__ __forceinline__ short f2bf(float f) {
    unsigned u = __float_as_uint(f);
    u += 0x7fff + ((u >> 16) & 1);   // round-to-nearest-even
    return (short)(u >> 16);
}
__device__ __forceinline__ float bf2f(short b) {
    return __uint_as_float(((unsigned)(unsigned short)b) << 16);
}

__device__ __forceinline__ void async16(const void* g, void* l) {
    __builtin_amdgcn_global_load_lds(
        (const __attribute__((address_space(1))) unsigned int*)g,
        (__attribute__((address_space(3))) unsigned int*)l, 16, 0, 0);
}

// ---------------- bf16 MFMA GEMM, double-buffered + XCD swizzle ----------------
__global__ __launch_bounds__(256) void gemm_mfma(const short* __restrict__ A,
                                                 const short* __restrict__ Bt,
                                                 short* __restrict__ xh_bf,
                                                 float* __restrict__ asrc,
                                                 float* __restrict__ adst,
                                                 int M, int MT) {
    const int lid = blockIdx.x;
    const int g = lid / 72, r = lid % 72;
    const int bmi = g * 8 + (r & 7);
    const int bni = r >> 3;
    if (bmi >= MT) return;
    const int bm = bmi * 128;
    const int bn = bni * 128;

    __shared__ short As[2][4096];
    __shared__ short Bs[2][4096];
    const int tid = threadIdx.x;
    const int lane = tid & 63;
    const int w = tid >> 6;
    const int wm = (w & 1) * 64;
    const int wn = (w >> 1) * 64;

    const int tt0 = tid, tt1 = 256 + tid;
    const int row0 = ((tt0 >> 6) << 4) | (tt0 & 15);
    const int col0 = ((tt0 >> 4) & 3) * 8;
    const int row1 = ((tt1 >> 6) << 4) | (tt1 & 15);
    const int col1 = ((tt1 >> 4) & 3) * 8;

    const short* gA0 = A + (size_t)(bm + row0) * KP + col0;
    const short* gA1 = A + (size_t)(bm + row1) * KP + col1;
    const short* gB0 = Bt + (size_t)(bn + row0) * KP + col0;
    const short* gB1 = Bt + (size_t)(bn + row1) * KP + col1;

    const int fr = lane & 15;
    const int kq = lane >> 4;

    floatx4 acc[4][4];
#pragma unroll
    for (int i = 0; i < 4; i++)
#pragma unroll
        for (int j = 0; j < 4; j++) acc[i][j] = (floatx4){0.f, 0.f, 0.f, 0.f};

    async16(gA0, &As[0][tt0 * 8]);
    async16(gA1, &As[0][tt1 * 8]);
    async16(gB0, &Bs[0][tt0 * 8]);
    async16(gB1, &Bs[0][tt1 * 8]);
    __syncthreads();

    int cur = 0;
    for (int k0 = 0; k0 < KP; k0 += 32) {
        const int nxt = cur ^ 1;
        const int k1 = k0 + 32;
        if (k1 < KP) {
            async16(gA0 + k1, &As[nxt][tt0 * 8]);
            async16(gA1 + k1, &As[nxt][tt1 * 8]);
            async16(gB0 + k1, &Bs[nxt][tt0 * 8]);
            async16(gB1 + k1, &Bs[nxt][tt1 * 8]);
        }
        shortx8 af[4], bfr[4];
#pragma unroll
        for (int i = 0; i < 4; i++) {
            af[i]  = *(const shortx8*)&As[cur][((wm >> 4) + i) * 512 + kq * 128 + fr * 8];
            bfr[i] = *(const shortx8*)&Bs[cur][((wn >> 4) + i) * 512 + kq * 128 + fr * 8];
        }
#pragma unroll
        for (int i = 0; i < 4; i++)
#pragma unroll
            for (int j = 0; j < 4; j++)
                acc[i][j] = __builtin_amdgcn_mfma_f32_16x16x32_bf16(af[i], bfr[j], acc[i][j], 0, 0, 0);
        __syncthreads();
        cur = nxt;
    }

    const int rbase = (lane >> 4) * 4;
    const int ccol = lane & 15;
#pragma unroll
    for (int j = 0; j < 4; j++) {
        int colbase = bn + wn + j * 16;
        if (colbase < FEAT) {
            int col = colbase + ccol;
#pragma unroll
            for (int i = 0; i < 4; i++)
#pragma unroll
                for (int r2 = 0; r2 < 4; r2++) {
                    int row = bm + wm + i * 16 + rbase + r2;
                    if (row < M) xh_bf[(size_t)row * FEAT + col] = f2bf(acc[i][j][r2]);
                }
        } else if (colbase == FEAT) {
            int c = ccol;
            float* tgt = (c < 8) ? asrc : adst;
            int h = c & 7;
#pragma unroll
            for (int i = 0; i < 4; i++)
#pragma unroll
                for (int r2 = 0; r2 < 4; r2++) {
                    int row = bm + wm + i * 16 + rbase + r2;
                    if (row < M) tgt[(size_t)row * NHEAD + h] = acc[i][j][r2];
                }
        }
    }
}

// ---------------- conversions / padding ----------------
__global__ void conv_x_bf(const float* __restrict__ x, short* __restrict__ out, int N) {
    int idx = blockIdx.x * 256 + threadIdx.x;   // index of 4-elem group
    int total = N * (FEAT / 4);
    if (idx >= total) return;
    int r = idx / (FEAT / 4), c4 = idx - r * (FEAT / 4);
    float4 v = *(const float4*)(x + (size_t)r * FEAT + c4 * 4);
    ushort4 o;
    o.x = (unsigned short)f2bf(v.x);
    o.y = (unsigned short)f2bf(v.y);
    o.z = (unsigned short)f2bf(v.z);
    o.w = (unsigned short)f2bf(v.w);
    *(ushort4*)(out + (size_t)r * KP + c4 * 4) = o;
}

__global__ void pad_bf(short* __restrict__ buf, int Mvalid) {
    int r = blockIdx.x;
    short* row = buf + (size_t)r * KP;
    if (r < Mvalid) {
        if (threadIdx.x < KP - FEAT) row[FEAT + threadIdx.x] = 0;
    } else {
        for (int c = threadIdx.x; c < KP; c += 64) row[c] = 0;
    }
}

__global__ void transpose_w(const float* __restrict__ Wl, short* __restrict__ Bt) {
    __shared__ float t[32][33];
    int kb = blockIdx.x * 32, nb = blockIdx.y * 32;
    int tx = threadIdx.x & 31, ty = threadIdx.x >> 5;
#pragma unroll
    for (int i = 0; i < 4; i++) {
        int k = kb + ty + i * 8, n = nb + tx;
        t[ty + i * 8][tx] = (k < FEAT && n < FEAT) ? Wl[(size_t)k * FEAT + n] : 0.f;
    }
    __syncthreads();
#pragma unroll
    for (int i = 0; i < 4; i++) {
        int n = nb + ty + i * 8, k = kb + tx;
        if (n < FEAT && k < FEAT) Bt[(size_t)n * KP + k] = f2bf(t[tx][ty + i * 8]);
    }
}

__global__ void wa_kernel(const float* __restrict__ W, const float* __restrict__ a_s,
                          const float* __restrict__ a_d, short* __restrict__ Bt3) {
    int t = blockIdx.x * 256 + threadIdx.x;
    if (t >= NLAYER * FEAT * NHEAD) return;
    int h = t & 7;
    int f = (t >> 3) % FEAT;
    int l = t / (FEAT * NHEAD);
    const float* wrow = W + (((size_t)l * FEAT + f) * NHEAD + h) * DHEAD;
    const float* as = a_s + ((size_t)l * NHEAD + h) * DHEAD;
    const float* ad = a_d + ((size_t)l * NHEAD + h) * DHEAD;
    float ws = 0.f, wd = 0.f;
    for (int d = 0; d < DHEAD; d++) {
        float wv = wrow[d];
        ws += wv * as[d];
        wd += wv * ad[d];
    }
    short* base = Bt3 + (size_t)l * NP * KP;
    base[(size_t)(FEAT + h) * KP + f] = f2bf(ws);
    base[(size_t)(FEAT + 8 + h) * KP + f] = f2bf(wd);
}

// ---------------- graph preprocessing ----------------
__global__ void build_edges(const int* __restrict__ ei, int E, int N,
                            int* __restrict__ src2, int* __restrict__ dst2,
                            int* __restrict__ deg) {
    int e = blockIdx.x * 256 + threadIdx.x;
    int E2 = E + N;
    if (e >= E2) return;
    int s, d;
    if (e < E) { s = ei[e]; d = ei[E + e]; }
    else       { s = e - E; d = e - E; }
    src2[e] = s;
    dst2[e] = d;
    atomicAdd(&deg[d], 1);
}

__global__ void scan_kernel(const int* __restrict__ deg, int* __restrict__ off,
                            int* __restrict__ cursor, int N) {
    __shared__ int wsum[16];
    __shared__ int carry_s;
    int tid = threadIdx.x;
    int lane = tid & 63, wid = tid >> 6;
    if (tid == 0) carry_s = 0;
    __syncthreads();
    for (int base = 0; base < N; base += 1024) {
        int i = base + tid;
        int v = (i < N) ? deg[i] : 0;
        int incl = v;
#pragma unroll
        for (int o = 1; o < 64; o <<= 1) {
            int u = __shfl_up(incl, o);
            if (lane >= o) incl += u;
        }
        if (lane == 63) wsum[wid] = incl;
        __syncthreads();
        if (wid == 0) {
            int wv = (lane < 16) ? wsum[lane] : 0;
            int wincl = wv;
#pragma unroll
            for (int o = 1; o < 16; o <<= 1) {
                int u = __shfl_up(wincl, o);
                if (lane >= o) wincl += u;
            }
            if (lane < 16) wsum[lane] = wincl - wv;
        }
        __syncthreads();
        int excl = carry_s + wsum[wid] + incl - v;
        if (i < N) { off[i] = excl; cursor[i] = excl; }
        int tot = 0;
        if (tid == 1023) tot = wsum[15] + incl;
        __syncthreads();
        if (tid == 1023) carry_s += tot;
        __syncthreads();
    }
    if (threadIdx.x == 0) off[N] = carry_s;
}

__global__ void scatter_k(const int* __restrict__ src2, const int* __restrict__ dst2,
                          int* __restrict__ cursor, int* __restrict__ ssrc, int E2) {
    int e = blockIdx.x * 256 + threadIdx.x;
    if (e >= E2) return;
    int d = dst2[e];
    int pos = atomicAdd(&cursor[d], 1);
    ssrc[pos] = src2[e];
}

__global__ void gstart_k(const int* __restrict__ batch, int* __restrict__ gstart, int N) {
    int n = blockIdx.x * 256 + threadIdx.x;
    if (n >= N) return;
    int b = batch[n];
    if (n == 0) {
        for (int g = 0; g <= b; g++) gstart[g] = 0;
    } else {
        int pb = batch[n - 1];
        for (int g = pb + 1; g <= b; g++) gstart[g] = n;
    }
    if (n == N - 1) {
        for (int g = b + 1; g <= NGRAPH; g++) gstart[g] = N;
    }
}

// ---- leaky-relu + segment softmax, ONE PASS (no max subtraction) ------------
// exp(v)/sum(exp(v)) is identical without the max shift; |v| here is O(8), and
// fminf(v,60) guards overflow. Halves the gather passes over asrc.
__global__ void att_softmax(const int* __restrict__ off, const int* __restrict__ ssrc,
                            const float* __restrict__ asrc, const float* __restrict__ adst,
                            float* __restrict__ p, float* __restrict__ dinv, int N) {
    int t = blockIdx.x * 256 + threadIdx.x;
    if (t >= N * NHEAD) return;
    int n = t >> 3, h = t & 7;
    int s = off[n], e = off[n + 1];
    float ad = adst[(size_t)n * NHEAD + h];
    float sum = 0.f;
    int j = s;
    for (; j + 4 <= e; j += 4) {
        float v0 = asrc[(size_t)ssrc[j] * NHEAD + h] + ad;
        float v1 = asrc[(size_t)ssrc[j + 1] * NHEAD + h] + ad;
        float v2 = asrc[(size_t)ssrc[j + 2] * NHEAD + h] + ad;
        float v3 = asrc[(size_t)ssrc[j + 3] * NHEAD + h] + ad;
        v0 = (v0 > 0.f) ? v0 : NEG_SLOPE * v0;
        v1 = (v1 > 0.f) ? v1 : NEG_SLOPE * v1;
        v2 = (v2 > 0.f) ? v2 : NEG_SLOPE * v2;
        v3 = (v3 > 0.f) ? v3 : NEG_SLOPE * v3;
        float e0 = __expf(fminf(v0, 60.f)), e1 = __expf(fminf(v1, 60.f));
        float e2 = __expf(fminf(v2, 60.f)), e3 = __expf(fminf(v3, 60.f));
        p[(size_t)j * NHEAD + h] = e0;
        p[(size_t)(j + 1) * NHEAD + h] = e1;
        p[(size_t)(j + 2) * NHEAD + h] = e2;
        p[(size_t)(j + 3) * NHEAD + h] = e3;
        sum += (e0 + e1) + (e2 + e3);
    }
    for (; j < e; j++) {
        float v = asrc[(size_t)ssrc[j] * NHEAD + h] + ad;
        v = (v > 0.f) ? v : NEG_SLOPE * v;
        float ex = __expf(fminf(v, 60.f));
        p[(size_t)j * NHEAD + h] = ex;
        sum += ex;
    }
    dinv[(size_t)n * NHEAD + h] = 1.0f / sum;
}

// ---------------- aggregation + BN + ReLU (softmax denom folded in) ----------
// R2 structure (1 node/block, 320 thr, 260 active, 8-B gathers, 2 p-loads/edge)
__global__ __launch_bounds__(320) void aggregate(
    const short* __restrict__ xh_bf, const float* __restrict__ p,
    const float* __restrict__ dinv,
    const int* __restrict__ off, const int* __restrict__ ssrc,
    const float* __restrict__ prev_f,     // fp32 residual (layer 1: x) or null
    const short* __restrict__ prev_bf,    // bf16 residual (layer 2: hA_bf) or null
    const float* __restrict__ b_att, const float* __restrict__ gamma,
    const float* __restrict__ beta, const float* __restrict__ mean,
    const float* __restrict__ var,
    short* __restrict__ hout_bf, int N) {
    int n = blockIdx.x;
    int t = threadIdx.x;
    if (t >= 260) return;
    int f0 = t * 4;
    int s = off[n], e = off[n + 1];
    const int hA = f0 / DHEAD;
    const int hB = (f0 + 3) / DHEAD;     // == hA for 126/130 of threads
    const int sp = hB * DHEAD - f0;      // feats i<sp use head hA (i in 0..3)
    float acc[4] = {0.f, 0.f, 0.f, 0.f};

    int j = s;
    for (; j + 8 <= e; j += 8) {
        int sj[8];
        ushort4 v[8];
#pragma unroll
        for (int u = 0; u < 8; u++) sj[u] = ssrc[j + u];
#pragma unroll
        for (int u = 0; u < 8; u++) v[u] = *(const ushort4*)(xh_bf + (size_t)sj[u] * FEAT + f0);
#pragma unroll
        for (int u = 0; u < 8; u++) {
            const float* pj = p + (size_t)(j + u) * NHEAD;
            float pa = pj[hA], pb = pj[hB];
            acc[0] += ((0 < sp) ? pa : pb) * bf2f((short)v[u].x);
            acc[1] += ((1 < sp) ? pa : pb) * bf2f((short)v[u].y);
            acc[2] += ((2 < sp) ? pa : pb) * bf2f((short)v[u].z);
            acc[3] += ((3 < sp) ? pa : pb) * bf2f((short)v[u].w);
        }
    }
    for (; j + 4 <= e; j += 4) {
        int sj[4];
        ushort4 v[4];
#pragma unroll
        for (int u = 0; u < 4; u++) sj[u] = ssrc[j + u];
#pragma unroll
        for (int u = 0; u < 4; u++) v[u] = *(const ushort4*)(xh_bf + (size_t)sj[u] * FEAT + f0);
#pragma unroll
        for (int u = 0; u < 4; u++) {
            const float* pj = p + (size_t)(j + u) * NHEAD;
            float pa = pj[hA], pb = pj[hB];
            acc[0] += ((0 < sp) ? pa : pb) * bf2f((short)v[u].x);
            acc[1] += ((1 < sp) ? pa : pb) * bf2f((short)v[u].y);
            acc[2] += ((2 < sp) ? pa : pb) * bf2f((short)v[u].z);
            acc[3] += ((3 < sp) ? pa : pb) * bf2f((short)v[u].w);
        }
    }
    for (; j < e; j++) {
        int src = ssrc[j];
        ushort4 v = *(const ushort4*)(xh_bf + (size_t)src * FEAT + f0);
        const float* pj = p + (size_t)j * NHEAD;
        float pa = pj[hA], pb = pj[hB];
        acc[0] += ((0 < sp) ? pa : pb) * bf2f((short)v.x);
        acc[1] += ((1 < sp) ? pa : pb) * bf2f((short)v.y);
        acc[2] += ((2 < sp) ? pa : pb) * bf2f((short)v.z);
        acc[3] += ((3 < sp) ? pa : pb) * bf2f((short)v.w);
    }

    // fold softmax denominator (per head)
    float da = dinv[(size_t)n * NHEAD + hA];
    float db = dinv[(size_t)n * NHEAD + hB];
    acc[0] *= (0 < sp) ? da : db;
    acc[1] *= (1 < sp) ? da : db;
    acc[2] *= (2 < sp) ? da : db;
    acc[3] *= (3 < sp) ? da : db;

    float4 bv = *(const float4*)(b_att + f0);
    float4 gv = *(const float4*)(gamma + f0);
    float4 be = *(const float4*)(beta + f0);
    float4 mv = *(const float4*)(mean + f0);
    float4 vv = *(const float4*)(var + f0);
    float z[4] = {acc[0] + bv.x, acc[1] + bv.y, acc[2] + bv.z, acc[3] + bv.w};
    if (prev_f) {
        float4 pv = *(const float4*)(prev_f + (size_t)n * FEAT + f0);
        z[0] += pv.x; z[1] += pv.y; z[2] += pv.z; z[3] += pv.w;
    }
    if (prev_bf) {
        ushort4 pv = *(const ushort4*)(prev_bf + (size_t)n * KP + f0);
        z[0] += bf2f((short)pv.x); z[1] += bf2f((short)pv.y);
        z[2] += bf2f((short)pv.z); z[3] += bf2f((short)pv.w);
    }
    float g4[4] = {gv.x, gv.y, gv.z, gv.w};
    float b4[4] = {be.x, be.y, be.z, be.w};
    float m4[4] = {mv.x, mv.y, mv.z, mv.w};
    float v4[4] = {vv.x, vv.y, vv.z, vv.w};
    ushort4 o;
    unsigned short* op = (unsigned short*)&o;
#pragma unroll
    for (int i = 0; i < 4; i++) {
        float zz = (z[i] - m4[i]) * rsqrtf(v4[i] + BN_EPS) * g4[i] + b4[i];
        op[i] = (unsigned short)f2bf(fmaxf(zz, 0.f));
    }
    *(ushort4*)(hout_bf + (size_t)n * KP + f0) = o;
}

// ---------------- pooling over contiguous node ranges ----------------
__global__ __launch_bounds__(320) void pool_k(const short* __restrict__ h,
                                              const int* __restrict__ gstart,
                                              float* __restrict__ pooled) {
    int g = blockIdx.x;
    int t = threadIdx.x;
    if (t >= 260) return;
    int f0 = t * 4;
    int s = gstart[g], e = gstart[g + 1];
    float acc[4] = {0.f, 0.f, 0.f, 0.f};
    int n = s;
    for (; n + 4 <= e; n += 4) {
        ushort4 v0 = *(const ushort4*)(h + (size_t)n * KP + f0);
        ushort4 v1 = *(const ushort4*)(h + (size_t)(n + 1) * KP + f0);
        ushort4 v2 = *(const ushort4*)(h + (size_t)(n + 2) * KP + f0);
        ushort4 v3 = *(const ushort4*)(h + (size_t)(n + 3) * KP + f0);
        acc[0] += bf2f((short)v0.x) + bf2f((short)v1.x) + bf2f((short)v2.x) + bf2f((short)v3.x);
        acc[1] += bf2f((short)v0.y) + bf2f((short)v1.y) + bf2f((short)v2.y) + bf2f((short)v3.y);
        acc[2] += bf2f((short)v0.z) + bf2f((short)v1.z) + bf2f((short)v2.z) + bf2f((short)v3.z);
        acc[3] += bf2f((short)v0.w) + bf2f((short)v1.w) + bf2f((short)v2.w) + bf2f((short)v3.w);
    }
    for (; n < e; n++) {
        ushort4 v = *(const ushort4*)(h + (size_t)n * KP + f0);
        acc[0] += bf2f((short)v.x);
        acc[1] += bf2f((short)v.y);
        acc[2] += bf2f((short)v.z);
        acc[3] += bf2f((short)v.w);
    }
    *(float4*)(pooled + (size_t)g * FEAT + f0) = make_float4(acc[0], acc[1], acc[2], acc[3]);
}

__global__ void final_k(const float* __restrict__ pooled, const int* __restrict__ gstart,
                        const float* __restrict__ W_out, const float* __restrict__ b_out,
                        float* __restrict__ out) {
    int g = blockIdx.x >> 1, c = blockIdx.x & 1;
    int lane = threadIdx.x;  // 64
    float ssum = 0.f;
    for (int f = lane; f < FEAT; f += 64) ssum += pooled[(size_t)g * FEAT + f] * W_out[f * 2 + c];
#pragma unroll
    for (int o = 1; o < 64; o <<= 1) ssum += __shfl_xor(ssum, o);
    if (lane == 0) {
        float cnt = (float)(gstart[g + 1] - gstart[g]);
        float inv = 1.0f / fmaxf(cnt, 1.0f);
        out[g * 2 + c] = ssum * inv + b_out[c];
    }
}

// ---------------- launch ----------------
extern "C" void kernel_launch(void* const* d_in, const int* in_sizes, int n_in,
                              void* d_out, int out_size, void* d_ws, size_t ws_size,
                              hipStream_t stream) {
    const float* x       = (const float*)d_in[0];
    const int*   ei      = (const int*)d_in[1];
    const int*   batch   = (const int*)d_in[2];
    const float* W       = (const float*)d_in[3];
    const float* a_src   = (const float*)d_in[4];
    const float* a_dst   = (const float*)d_in[5];
    const float* b_att   = (const float*)d_in[6];
    const float* gamma   = (const float*)d_in[7];
    const float* beta    = (const float*)d_in[8];
    const float* r_mean  = (const float*)d_in[9];
    const float* r_var   = (const float*)d_in[10];
    const float* W_out   = (const float*)d_in[11];
    const float* b_out   = (const float*)d_in[12];
    float* out = (float*)d_out;

    const int N = in_sizes[0] / FEAT;
    const int E = in_sizes[1] / 2;
    const int E2 = E + N;
    const int MT = (N + 127) / 128;
    const int Mp = MT * 128;
    const int MTpad = ((MT + 7) / 8) * 8;

    char* w = (char*)d_ws;
    auto alloc = [&](size_t bytes) {
        void* pp = (void*)w;
        w += (bytes + 255) & ~(size_t)255;
        return pp;
    };
    short* xh_bf  = (short*)alloc((size_t)N * FEAT * 2);
    short* x_bf   = (short*)alloc((size_t)Mp * KP * 2);   // layer-0 A; reused as layer-3 h
    short* hA_bf  = (short*)alloc((size_t)Mp * KP * 2);
    short* hB_bf  = (short*)alloc((size_t)Mp * KP * 2);
    short* Bt3    = (short*)alloc((size_t)NLAYER * NP * KP * 2);
    float* p      = (float*)alloc((size_t)E2 * NHEAD * 4);
    float* asrc   = (float*)alloc((size_t)N * NHEAD * 4);
    float* adst   = (float*)alloc((size_t)N * NHEAD * 4);
    float* dinv   = (float*)alloc((size_t)N * NHEAD * 4);
    int*   src2   = (int*)alloc((size_t)E2 * 4);
    int*   dst2   = (int*)alloc((size_t)E2 * 4);
    int*   ssrc   = (int*)alloc((size_t)E2 * 4);
    int*   deg    = (int*)alloc((size_t)N * 4);
    int*   off    = (int*)alloc((size_t)(N + 1) * 4);
    int*   cursor = (int*)alloc((size_t)N * 4);
    int*   gstart = (int*)alloc((size_t)(NGRAPH + 1) * 4);
    float* pooled = (float*)alloc((size_t)NGRAPH * FEAT * 4);

    hipMemsetAsync(deg, 0, (size_t)N * 4, stream);
    hipMemsetAsync(Bt3, 0, (size_t)NLAYER * NP * KP * 2, stream);

    conv_x_bf<<<(N * (FEAT / 4) + 255) / 256, 256, 0, stream>>>(x, x_bf, N);
    pad_bf<<<Mp, 64, 0, stream>>>(x_bf, N);
    pad_bf<<<Mp, 64, 0, stream>>>(hA_bf, N);
    pad_bf<<<Mp, 64, 0, stream>>>(hB_bf, N);
    dim3 tgrid((FEAT + 31) / 32, (FEAT + 31) / 32);
    for (int l = 0; l < NLAYER; l++)
        transpose_w<<<tgrid, 256, 0, stream>>>(W + (size_t)l * FEAT * FEAT,
                                               Bt3 + (size_t)l * NP * KP);
    wa_kernel<<<(NLAYER * FEAT * NHEAD + 255) / 256, 256, 0, stream>>>(W, a_src, a_dst, Bt3);

    build_edges<<<(E2 + 255) / 256, 256, 0, stream>>>(ei, E, N, src2, dst2, deg);
    scan_kernel<<<1, 1024, 0, stream>>>(deg, off, cursor, N);
    scatter_k<<<(E2 + 255) / 256, 256, 0, stream>>>(src2, dst2, cursor, ssrc, E2);
    gstart_k<<<(N + 255) / 256, 256, 0, stream>>>(batch, gstart, N);

    const short* hin[NLAYER]     = {x_bf, hA_bf, hB_bf};
    const float* prevf[NLAYER]   = {nullptr, x, nullptr};
    const short* prevbf[NLAYER]  = {nullptr, nullptr, hA_bf};
    short* houtl[NLAYER]         = {hA_bf, hB_bf, x_bf};

    for (int l = 0; l < NLAYER; l++) {
        gemm_mfma<<<MTpad * 9, 256, 0, stream>>>(hin[l], Bt3 + (size_t)l * NP * KP,
                                                 xh_bf, asrc, adst, N, MT);
        att_softmax<<<(N * NHEAD + 255) / 256, 256, 0, stream>>>(off, ssrc, asrc, adst, p, dinv, N);
        aggregate<<<N, 320, 0, stream>>>(xh_bf, p, dinv, off, ssrc, prevf[l], prevbf[l],
                                         b_att + l * FEAT, gamma + l * FEAT, beta + l * FEAT,
                                         r_mean + l * FEAT, r_var + l * FEAT,
                                         houtl[l], N);
    }

    pool_k<<<NGRAPH, 320, 0, stream>>>(x_bf, gstart, pooled);
    final_k<<<NGRAPH * 2, 64, 0, stream>>>(pooled, gstart, W_out, b_out, out);
}

// Round 5
// 1117.645 us; speedup vs baseline: 1.2433x; 1.0021x over previous
//
#include <hip/hip_runtime.h>
#include <hip/hip_bf16.h>
#include <math.h>

#define FEAT 1040
#define NHEAD 8
#define DHEAD 130
#define NLAYER 3
#define NGRAPH 64
#define NEG_SLOPE 0.2f
#define BN_EPS 1e-5f
#define KP 1056   // FEAT padded to multiple of 32 (K of GEMM)
#define NP 1152   // FEAT padded to multiple of 128; cols 1040..1055 = wa_src/wa_dst
#define NKT (KP / 32)   // 33 K-tiles

typedef float floatx4 __attribute__((ext_vector_type(4)));
typedef short shortx8 __attribute__((ext_vector_type(8)));

__device__ __forceinline__ short f2bf(float f) {
    unsigned u = __float_as_uint(f);
    u += 0x7fff + ((u >> 16) & 1);   // round-to-nearest-even
    return (short)(u >> 16);
}
__device__ __forceinline__ float bf2f(short b) {
    return __uint_as_float(((unsigned)(unsigned short)b) << 16);
}

__device__ __forceinline__ void async16(const void* g, void* l) {
    __builtin_amdgcn_global_load_lds(
        (const __attribute__((address_space(1))) unsigned int*)g,
        (__attribute__((address_space(3))) unsigned int*)l, 16, 0, 0);
}

// ---------------- bf16 MFMA GEMM ----------------
// 3-buffer LDS ring, prefetch distance 2, counted s_waitcnt vmcnt(4) (never a
// full drain in the main loop). Loads into a ring slot are issued only AFTER
// the barrier that proves all ds_reads of that slot completed -> race-free by
// construction. One s_barrier per K-step (vs __syncthreads drain before).
__global__ __launch_bounds__(256) void gemm_mfma(const short* __restrict__ A,
                                                 const short* __restrict__ Bt,
                                                 short* __restrict__ xh_bf,
                                                 float* __restrict__ asrc,
                                                 float* __restrict__ adst,
                                                 int M, int MT) {
    const int lid = blockIdx.x;
    const int g = lid / 72, r = lid % 72;
    const int bmi = g * 8 + (r & 7);
    const int bni = r >> 3;
    if (bmi >= MT) return;
    const int bm = bmi * 128;
    const int bn = bni * 128;

    __shared__ short As[3][4096];
    __shared__ short Bs[3][4096];
    const int tid = threadIdx.x;
    const int lane = tid & 63;
    const int w = tid >> 6;
    const int wm = (w & 1) * 64;
    const int wn = (w >> 1) * 64;

    const int tt0 = tid, tt1 = 256 + tid;
    const int row0 = ((tt0 >> 6) << 4) | (tt0 & 15);
    const int col0 = ((tt0 >> 4) & 3) * 8;
    const int row1 = ((tt1 >> 6) << 4) | (tt1 & 15);
    const int col1 = ((tt1 >> 4) & 3) * 8;

    const short* gA0 = A + (size_t)(bm + row0) * KP + col0;
    const short* gA1 = A + (size_t)(bm + row1) * KP + col1;
    const short* gB0 = Bt + (size_t)(bn + row0) * KP + col0;
    const short* gB1 = Bt + (size_t)(bn + row1) * KP + col1;

    const int fr = lane & 15;
    const int kq = lane >> 4;

    floatx4 acc[4][4];
#pragma unroll
    for (int i = 0; i < 4; i++)
#pragma unroll
        for (int j = 0; j < 4; j++) acc[i][j] = (floatx4){0.f, 0.f, 0.f, 0.f};

    // prologue: stage tiles 0 and 1 (8 loads/thread in flight)
    async16(gA0, &As[0][tt0 * 8]);
    async16(gA1, &As[0][tt1 * 8]);
    async16(gB0, &Bs[0][tt0 * 8]);
    async16(gB1, &Bs[0][tt1 * 8]);
    async16(gA0 + 32, &As[1][tt0 * 8]);
    async16(gA1 + 32, &As[1][tt1 * 8]);
    async16(gB0 + 32, &Bs[1][tt0 * 8]);
    async16(gB1 + 32, &Bs[1][tt1 * 8]);

    int cur = 0;
    for (int it = 0; it < NKT; ++it) {
        // wait: tile it's 4 loads done (the newest 4 = tile it+1 stay in flight)
        if (it == NKT - 1) {
            asm volatile("s_waitcnt vmcnt(0)" ::: "memory");
        } else {
            asm volatile("s_waitcnt vmcnt(4)" ::: "memory");
        }
        __builtin_amdgcn_s_barrier();
        __builtin_amdgcn_sched_barrier(0);
        // prefetch tile it+2 into the slot last read at iter it-1 (all waves
        // provably past that read: they crossed this iteration's barrier)
        if (it + 2 < NKT) {
            int pf = cur + 2; if (pf >= 3) pf -= 3;
            const int kp = (it + 2) * 32;
            async16(gA0 + kp, &As[pf][tt0 * 8]);
            async16(gA1 + kp, &As[pf][tt1 * 8]);
            async16(gB0 + kp, &Bs[pf][tt0 * 8]);
            async16(gB1 + kp, &Bs[pf][tt1 * 8]);
        }
        shortx8 af[4], bfr[4];
#pragma unroll
        for (int i = 0; i < 4; i++) {
            af[i]  = *(const shortx8*)&As[cur][((wm >> 4) + i) * 512 + kq * 128 + fr * 8];
            bfr[i] = *(const shortx8*)&Bs[cur][((wn >> 4) + i) * 512 + kq * 128 + fr * 8];
        }
#pragma unroll
        for (int i = 0; i < 4; i++)
#pragma unroll
            for (int j = 0; j < 4; j++)
                acc[i][j] = __builtin_amdgcn_mfma_f32_16x16x32_bf16(af[i], bfr[j], acc[i][j], 0, 0, 0);
        cur = (cur == 2) ? 0 : cur + 1;
    }

    const int rbase = (lane >> 4) * 4;
    const int ccol = lane & 15;
#pragma unroll
    for (int j = 0; j < 4; j++) {
        int colbase = bn + wn + j * 16;
        if (colbase < FEAT) {
            int col = colbase + ccol;
#pragma unroll
            for (int i = 0; i < 4; i++)
#pragma unroll
                for (int r2 = 0; r2 < 4; r2++) {
                    int row = bm + wm + i * 16 + rbase + r2;
                    if (row < M) xh_bf[(size_t)row * FEAT + col] = f2bf(acc[i][j][r2]);
                }
        } else if (colbase == FEAT) {
            int c = ccol;
            float* tgt = (c < 8) ? asrc : adst;
            int h = c & 7;
#pragma unroll
            for (int i = 0; i < 4; i++)
#pragma unroll
                for (int r2 = 0; r2 < 4; r2++) {
                    int row = bm + wm + i * 16 + rbase + r2;
                    if (row < M) tgt[(size_t)row * NHEAD + h] = acc[i][j][r2];
                }
        }
    }
}

// ---------------- conversions / padding ----------------
__global__ void conv_x_bf(const float* __restrict__ x, short* __restrict__ out, int N) {
    int idx = blockIdx.x * 256 + threadIdx.x;   // index of 4-elem group
    int total = N * (FEAT / 4);
    if (idx >= total) return;
    int r = idx / (FEAT / 4), c4 = idx - r * (FEAT / 4);
    float4 v = *(const float4*)(x + (size_t)r * FEAT + c4 * 4);
    ushort4 o;
    o.x = (unsigned short)f2bf(v.x);
    o.y = (unsigned short)f2bf(v.y);
    o.z = (unsigned short)f2bf(v.z);
    o.w = (unsigned short)f2bf(v.w);
    *(ushort4*)(out + (size_t)r * KP + c4 * 4) = o;
}

__global__ void pad_bf(short* __restrict__ buf, int Mvalid) {
    int r = blockIdx.x;
    short* row = buf + (size_t)r * KP;
    if (r < Mvalid) {
        if (threadIdx.x < KP - FEAT) row[FEAT + threadIdx.x] = 0;
    } else {
        for (int c = threadIdx.x; c < KP; c += 64) row[c] = 0;
    }
}

__global__ void transpose_w(const float* __restrict__ Wl, short* __restrict__ Bt) {
    __shared__ float t[32][33];
    int kb = blockIdx.x * 32, nb = blockIdx.y * 32;
    int tx = threadIdx.x & 31, ty = threadIdx.x >> 5;
#pragma unroll
    for (int i = 0; i < 4; i++) {
        int k = kb + ty + i * 8, n = nb + tx;
        t[ty + i * 8][tx] = (k < FEAT && n < FEAT) ? Wl[(size_t)k * FEAT + n] : 0.f;
    }
    __syncthreads();
#pragma unroll
    for (int i = 0; i < 4; i++) {
        int n = nb + ty + i * 8, k = kb + tx;
        if (n < FEAT && k < FEAT) Bt[(size_t)n * KP + k] = f2bf(t[tx][ty + i * 8]);
    }
}

__global__ void wa_kernel(const float* __restrict__ W, const float* __restrict__ a_s,
                          const float* __restrict__ a_d, short* __restrict__ Bt3) {
    int t = blockIdx.x * 256 + threadIdx.x;
    if (t >= NLAYER * FEAT * NHEAD) return;
    int h = t & 7;
    int f = (t >> 3) % FEAT;
    int l = t / (FEAT * NHEAD);
    const float* wrow = W + (((size_t)l * FEAT + f) * NHEAD + h) * DHEAD;
    const float* as = a_s + ((size_t)l * NHEAD + h) * DHEAD;
    const float* ad = a_d + ((size_t)l * NHEAD + h) * DHEAD;
    float ws = 0.f, wd = 0.f;
    for (int d = 0; d < DHEAD; d++) {
        float wv = wrow[d];
        ws += wv * as[d];
        wd += wv * ad[d];
    }
    short* base = Bt3 + (size_t)l * NP * KP;
    base[(size_t)(FEAT + h) * KP + f] = f2bf(ws);
    base[(size_t)(FEAT + 8 + h) * KP + f] = f2bf(wd);
}

// ---------------- graph preprocessing ----------------
__global__ void build_edges(const int* __restrict__ ei, int E, int N,
                            int* __restrict__ src2, int* __restrict__ dst2,
                            int* __restrict__ deg) {
    int e = blockIdx.x * 256 + threadIdx.x;
    int E2 = E + N;
    if (e >= E2) return;
    int s, d;
    if (e < E) { s = ei[e]; d = ei[E + e]; }
    else       { s = e - E; d = e - E; }
    src2[e] = s;
    dst2[e] = d;
    atomicAdd(&deg[d], 1);
}

__global__ void scan_kernel(const int* __restrict__ deg, int* __restrict__ off,
                            int* __restrict__ cursor, int N) {
    __shared__ int wsum[16];
    __shared__ int carry_s;
    int tid = threadIdx.x;
    int lane = tid & 63, wid = tid >> 6;
    if (tid == 0) carry_s = 0;
    __syncthreads();
    for (int base = 0; base < N; base += 1024) {
        int i = base + tid;
        int v = (i < N) ? deg[i] : 0;
        int incl = v;
#pragma unroll
        for (int o = 1; o < 64; o <<= 1) {
            int u = __shfl_up(incl, o);
            if (lane >= o) incl += u;
        }
        if (lane == 63) wsum[wid] = incl;
        __syncthreads();
        if (wid == 0) {
            int wv = (lane < 16) ? wsum[lane] : 0;
            int wincl = wv;
#pragma unroll
            for (int o = 1; o < 16; o <<= 1) {
                int u = __shfl_up(wincl, o);
                if (lane >= o) wincl += u;
            }
            if (lane < 16) wsum[lane] = wincl - wv;
        }
        __syncthreads();
        int excl = carry_s + wsum[wid] + incl - v;
        if (i < N) { off[i] = excl; cursor[i] = excl; }
        int tot = 0;
        if (tid == 1023) tot = wsum[15] + incl;
        __syncthreads();
        if (tid == 1023) carry_s += tot;
        __syncthreads();
    }
    if (threadIdx.x == 0) off[N] = carry_s;
}

__global__ void scatter_k(const int* __restrict__ src2, const int* __restrict__ dst2,
                          int* __restrict__ cursor, int* __restrict__ ssrc, int E2) {
    int e = blockIdx.x * 256 + threadIdx.x;
    if (e >= E2) return;
    int d = dst2[e];
    int pos = atomicAdd(&cursor[d], 1);
    ssrc[pos] = src2[e];
}

__global__ void gstart_k(const int* __restrict__ batch, int* __restrict__ gstart, int N) {
    int n = blockIdx.x * 256 + threadIdx.x;
    if (n >= N) return;
    int b = batch[n];
    if (n == 0) {
        for (int g = 0; g <= b; g++) gstart[g] = 0;
    } else {
        int pb = batch[n - 1];
        for (int g = pb + 1; g <= b; g++) gstart[g] = n;
    }
    if (n == N - 1) {
        for (int g = b + 1; g <= NGRAPH; g++) gstart[g] = N;
    }
}

// ---- leaky-relu + segment softmax, ONE PASS (no max subtraction) ------------
__global__ void att_softmax(const int* __restrict__ off, const int* __restrict__ ssrc,
                            const float* __restrict__ asrc, const float* __restrict__ adst,
                            float* __restrict__ p, float* __restrict__ dinv, int N) {
    int t = blockIdx.x * 256 + threadIdx.x;
    if (t >= N * NHEAD) return;
    int n = t >> 3, h = t & 7;
    int s = off[n], e = off[n + 1];
    float ad = adst[(size_t)n * NHEAD + h];
    float sum = 0.f;
    int j = s;
    for (; j + 4 <= e; j += 4) {
        float v0 = asrc[(size_t)ssrc[j] * NHEAD + h] + ad;
        float v1 = asrc[(size_t)ssrc[j + 1] * NHEAD + h] + ad;
        float v2 = asrc[(size_t)ssrc[j + 2] * NHEAD + h] + ad;
        float v3 = asrc[(size_t)ssrc[j + 3] * NHEAD + h] + ad;
        v0 = (v0 > 0.f) ? v0 : NEG_SLOPE * v0;
        v1 = (v1 > 0.f) ? v1 : NEG_SLOPE * v1;
        v2 = (v2 > 0.f) ? v2 : NEG_SLOPE * v2;
        v3 = (v3 > 0.f) ? v3 : NEG_SLOPE * v3;
        float e0 = __expf(fminf(v0, 60.f)), e1 = __expf(fminf(v1, 60.f));
        float e2 = __expf(fminf(v2, 60.f)), e3 = __expf(fminf(v3, 60.f));
        p[(size_t)j * NHEAD + h] = e0;
        p[(size_t)(j + 1) * NHEAD + h] = e1;
        p[(size_t)(j + 2) * NHEAD + h] = e2;
        p[(size_t)(j + 3) * NHEAD + h] = e3;
        sum += (e0 + e1) + (e2 + e3);
    }
    for (; j < e; j++) {
        float v = asrc[(size_t)ssrc[j] * NHEAD + h] + ad;
        v = (v > 0.f) ? v : NEG_SLOPE * v;
        float ex = __expf(fminf(v, 60.f));
        p[(size_t)j * NHEAD + h] = ex;
        sum += ex;
    }
    dinv[(size_t)n * NHEAD + h] = 1.0f / sum;
}

// ---------------- aggregation + BN + ReLU (softmax denom folded in) ----------
// R2 structure (1 node/block, 320 thr, 260 active, 8-B gathers, 2 p-loads/edge)
__global__ __launch_bounds__(320) void aggregate(
    const short* __restrict__ xh_bf, const float* __restrict__ p,
    const float* __restrict__ dinv,
    const int* __restrict__ off, const int* __restrict__ ssrc,
    const float* __restrict__ prev_f,     // fp32 residual (layer 1: x) or null
    const short* __restrict__ prev_bf,    // bf16 residual (layer 2: hA_bf) or null
    const float* __restrict__ b_att, const float* __restrict__ gamma,
    const float* __restrict__ beta, const float* __restrict__ mean,
    const float* __restrict__ var,
    short* __restrict__ hout_bf, int N) {
    int n = blockIdx.x;
    int t = threadIdx.x;
    if (t >= 260) return;
    int f0 = t * 4;
    int s = off[n], e = off[n + 1];
    const int hA = f0 / DHEAD;
    const int hB = (f0 + 3) / DHEAD;     // == hA for 126/130 of threads
    const int sp = hB * DHEAD - f0;      // feats i<sp use head hA (i in 0..3)
    float acc[4] = {0.f, 0.f, 0.f, 0.f};

    int j = s;
    for (; j + 8 <= e; j += 8) {
        int sj[8];
        ushort4 v[8];
#pragma unroll
        for (int u = 0; u < 8; u++) sj[u] = ssrc[j + u];
#pragma unroll
        for (int u = 0; u < 8; u++) v[u] = *(const ushort4*)(xh_bf + (size_t)sj[u] * FEAT + f0);
#pragma unroll
        for (int u = 0; u < 8; u++) {
            const float* pj = p + (size_t)(j + u) * NHEAD;
            float pa = pj[hA], pb = pj[hB];
            acc[0] += ((0 < sp) ? pa : pb) * bf2f((short)v[u].x);
            acc[1] += ((1 < sp) ? pa : pb) * bf2f((short)v[u].y);
            acc[2] += ((2 < sp) ? pa : pb) * bf2f((short)v[u].z);
            acc[3] += ((3 < sp) ? pa : pb) * bf2f((short)v[u].w);
        }
    }
    for (; j + 4 <= e; j += 4) {
        int sj[4];
        ushort4 v[4];
#pragma unroll
        for (int u = 0; u < 4; u++) sj[u] = ssrc[j + u];
#pragma unroll
        for (int u = 0; u < 4; u++) v[u] = *(const ushort4*)(xh_bf + (size_t)sj[u] * FEAT + f0);
#pragma unroll
        for (int u = 0; u < 4; u++) {
            const float* pj = p + (size_t)(j + u) * NHEAD;
            float pa = pj[hA], pb = pj[hB];
            acc[0] += ((0 < sp) ? pa : pb) * bf2f((short)v[u].x);
            acc[1] += ((1 < sp) ? pa : pb) * bf2f((short)v[u].y);
            acc[2] += ((2 < sp) ? pa : pb) * bf2f((short)v[u].z);
            acc[3] += ((3 < sp) ? pa : pb) * bf2f((short)v[u].w);
        }
    }
    for (; j < e; j++) {
        int src = ssrc[j];
        ushort4 v = *(const ushort4*)(xh_bf + (size_t)src * FEAT + f0);
        const float* pj = p + (size_t)j * NHEAD;
        float pa = pj[hA], pb = pj[hB];
        acc[0] += ((0 < sp) ? pa : pb) * bf2f((short)v.x);
        acc[1] += ((1 < sp) ? pa : pb) * bf2f((short)v.y);
        acc[2] += ((2 < sp) ? pa : pb) * bf2f((short)v.z);
        acc[3] += ((3 < sp) ? pa : pb) * bf2f((short)v.w);
    }

    // fold softmax denominator (per head)
    float da = dinv[(size_t)n * NHEAD + hA];
    float db = dinv[(size_t)n * NHEAD + hB];
    acc[0] *= (0 < sp) ? da : db;
    acc[1] *= (1 < sp) ? da : db;
    acc[2] *= (2 < sp) ? da : db;
    acc[3] *= (3 < sp) ? da : db;

    float4 bv = *(const float4*)(b_att + f0);
    float4 gv = *(const float4*)(gamma + f0);
    float4 be = *(const float4*)(beta + f0);
    float4 mv = *(const float4*)(mean + f0);
    float4 vv = *(const float4*)(var + f0);
    float z[4] = {acc[0] + bv.x, acc[1] + bv.y, acc[2] + bv.z, acc[3] + bv.w};
    if (prev_f) {
        float4 pv = *(const float4*)(prev_f + (size_t)n * FEAT + f0);
        z[0] += pv.x; z[1] += pv.y; z[2] += pv.z; z[3] += pv.w;
    }
    if (prev_bf) {
        ushort4 pv = *(const ushort4*)(prev_bf + (size_t)n * KP + f0);
        z[0] += bf2f((short)pv.x); z[1] += bf2f((short)pv.y);
        z[2] += bf2f((short)pv.z); z[3] += bf2f((short)pv.w);
    }
    float g4[4] = {gv.x, gv.y, gv.z, gv.w};
    float b4[4] = {be.x, be.y, be.z, be.w};
    float m4[4] = {mv.x, mv.y, mv.z, mv.w};
    float v4[4] = {vv.x, vv.y, vv.z, vv.w};
    ushort4 o;
    unsigned short* op = (unsigned short*)&o;
#pragma unroll
    for (int i = 0; i < 4; i++) {
        float zz = (z[i] - m4[i]) * rsqrtf(v4[i] + BN_EPS) * g4[i] + b4[i];
        op[i] = (unsigned short)f2bf(fmaxf(zz, 0.f));
    }
    *(ushort4*)(hout_bf + (size_t)n * KP + f0) = o;
}

// ---------------- pooling over contiguous node ranges ----------------
__global__ __launch_bounds__(320) void pool_k(const short* __restrict__ h,
                                              const int* __restrict__ gstart,
                                              float* __restrict__ pooled) {
    int g = blockIdx.x;
    int t = threadIdx.x;
    if (t >= 260) return;
    int f0 = t * 4;
    int s = gstart[g], e = gstart[g + 1];
    float acc[4] = {0.f, 0.f, 0.f, 0.f};
    int n = s;
    for (; n + 4 <= e; n += 4) {
        ushort4 v0 = *(const ushort4*)(h + (size_t)n * KP + f0);
        ushort4 v1 = *(const ushort4*)(h + (size_t)(n + 1) * KP + f0);
        ushort4 v2 = *(const ushort4*)(h + (size_t)(n + 2) * KP + f0);
        ushort4 v3 = *(const ushort4*)(h + (size_t)(n + 3) * KP + f0);
        acc[0] += bf2f((short)v0.x) + bf2f((short)v1.x) + bf2f((short)v2.x) + bf2f((short)v3.x);
        acc[1] += bf2f((short)v0.y) + bf2f((short)v1.y) + bf2f((short)v2.y) + bf2f((short)v3.y);
        acc[2] += bf2f((short)v0.z) + bf2f((short)v1.z) + bf2f((short)v2.z) + bf2f((short)v3.z);
        acc[3] += bf2f((short)v0.w) + bf2f((short)v1.w) + bf2f((short)v2.w) + bf2f((short)v3.w);
    }
    for (; n < e; n++) {
        ushort4 v = *(const ushort4*)(h + (size_t)n * KP + f0);
        acc[0] += bf2f((short)v.x);
        acc[1] += bf2f((short)v.y);
        acc[2] += bf2f((short)v.z);
        acc[3] += bf2f((short)v.w);
    }
    *(float4*)(pooled + (size_t)g * FEAT + f0) = make_float4(acc[0], acc[1], acc[2], acc[3]);
}

__global__ void final_k(const float* __restrict__ pooled, const int* __restrict__ gstart,
                        const float* __restrict__ W_out, const float* __restrict__ b_out,
                        float* __restrict__ out) {
    int g = blockIdx.x >> 1, c = blockIdx.x & 1;
    int lane = threadIdx.x;  // 64
    float ssum = 0.f;
    for (int f = lane; f < FEAT; f += 64) ssum += pooled[(size_t)g * FEAT + f] * W_out[f * 2 + c];
#pragma unroll
    for (int o = 1; o < 64; o <<= 1) ssum += __shfl_xor(ssum, o);
    if (lane == 0) {
        float cnt = (float)(gstart[g + 1] - gstart[g]);
        float inv = 1.0f / fmaxf(cnt, 1.0f);
        out[g * 2 + c] = ssum * inv + b_out[c];
    }
}

// ---------------- launch ----------------
extern "C" void kernel_launch(void* const* d_in, const int* in_sizes, int n_in,
                              void* d_out, int out_size, void* d_ws, size_t ws_size,
                              hipStream_t stream) {
    const float* x       = (const float*)d_in[0];
    const int*   ei      = (const int*)d_in[1];
    const int*   batch   = (const int*)d_in[2];
    const float* W       = (const float*)d_in[3];
    const float* a_src   = (const float*)d_in[4];
    const float* a_dst   = (const float*)d_in[5];
    const float* b_att   = (const float*)d_in[6];
    const float* gamma   = (const float*)d_in[7];
    const float* beta    = (const float*)d_in[8];
    const float* r_mean  = (const float*)d_in[9];
    const float* r_var   = (const float*)d_in[10];
    const float* W_out   = (const float*)d_in[11];
    const float* b_out   = (const float*)d_in[12];
    float* out = (float*)d_out;

    const int N = in_sizes[0] / FEAT;
    const int E = in_sizes[1] / 2;
    const int E2 = E + N;
    const int MT = (N + 127) / 128;
    const int Mp = MT * 128;
    const int MTpad = ((MT + 7) / 8) * 8;

    char* w = (char*)d_ws;
    auto alloc = [&](size_t bytes) {
        void* pp = (void*)w;
        w += (bytes + 255) & ~(size_t)255;
        return pp;
    };
    short* xh_bf  = (short*)alloc((size_t)N * FEAT * 2);
    short* x_bf   = (short*)alloc((size_t)Mp * KP * 2);   // layer-0 A; reused as layer-3 h
    short* hA_bf  = (short*)alloc((size_t)Mp * KP * 2);
    short* hB_bf  = (short*)alloc((size_t)Mp * KP * 2);
    short* Bt3    = (short*)alloc((size_t)NLAYER * NP * KP * 2);
    float* p      = (float*)alloc((size_t)E2 * NHEAD * 4);
    float* asrc   = (float*)alloc((size_t)N * NHEAD * 4);
    float* adst   = (float*)alloc((size_t)N * NHEAD * 4);
    float* dinv   = (float*)alloc((size_t)N * NHEAD * 4);
    int*   src2   = (int*)alloc((size_t)E2 * 4);
    int*   dst2   = (int*)alloc((size_t)E2 * 4);
    int*   ssrc   = (int*)alloc((size_t)E2 * 4);
    int*   deg    = (int*)alloc((size_t)N * 4);
    int*   off    = (int*)alloc((size_t)(N + 1) * 4);
    int*   cursor = (int*)alloc((size_t)N * 4);
    int*   gstart = (int*)alloc((size_t)(NGRAPH + 1) * 4);
    float* pooled = (float*)alloc((size_t)NGRAPH * FEAT * 4);

    hipMemsetAsync(deg, 0, (size_t)N * 4, stream);
    hipMemsetAsync(Bt3, 0, (size_t)NLAYER * NP * KP * 2, stream);

    conv_x_bf<<<(N * (FEAT / 4) + 255) / 256, 256, 0, stream>>>(x, x_bf, N);
    pad_bf<<<Mp, 64, 0, stream>>>(x_bf, N);
    pad_bf<<<Mp, 64, 0, stream>>>(hA_bf, N);
    pad_bf<<<Mp, 64, 0, stream>>>(hB_bf, N);
    dim3 tgrid((FEAT + 31) / 32, (FEAT + 31) / 32);
    for (int l = 0; l < NLAYER; l++)
        transpose_w<<<tgrid, 256, 0, stream>>>(W + (size_t)l * FEAT * FEAT,
                                               Bt3 + (size_t)l * NP * KP);
    wa_kernel<<<(NLAYER * FEAT * NHEAD + 255) / 256, 256, 0, stream>>>(W, a_src, a_dst, Bt3);

    build_edges<<<(E2 + 255) / 256, 256, 0, stream>>>(ei, E, N, src2, dst2, deg);
    scan_kernel<<<1, 1024, 0, stream>>>(deg, off, cursor, N);
    scatter_k<<<(E2 + 255) / 256, 256, 0, stream>>>(src2, dst2, cursor, ssrc, E2);
    gstart_k<<<(N + 255) / 256, 256, 0, stream>>>(batch, gstart, N);

    const short* hin[NLAYER]     = {x_bf, hA_bf, hB_bf};
    const float* prevf[NLAYER]   = {nullptr, x, nullptr};
    const short* prevbf[NLAYER]  = {nullptr, nullptr, hA_bf};
    short* houtl[NLAYER]         = {hA_bf, hB_bf, x_bf};

    for (int l = 0; l < NLAYER; l++) {
        gemm_mfma<<<MTpad * 9, 256, 0, stream>>>(hin[l], Bt3 + (size_t)l * NP * KP,
                                                 xh_bf, asrc, adst, N, MT);
        att_softmax<<<(N * NHEAD + 255) / 256, 256, 0, stream>>>(off, ssrc, asrc, adst, p, dinv, N);
        aggregate<<<N, 320, 0, stream>>>(xh_bf, p, dinv, off, ssrc, prevf[l], prevbf[l],
                                         b_att + l * FEAT, gamma + l * FEAT, beta + l * FEAT,
                                         r_mean + l * FEAT, r_var + l * FEAT,
                                         houtl[l], N);
    }

    pool_k<<<NGRAPH, 320, 0, stream>>>(x_bf, gstart, pooled);
    final_k<<<NGRAPH * 2, 64, 0, stream>>>(pooled, gstart, W_out, b_out, out);
}

// Round 6
// 1101.938 us; speedup vs baseline: 1.2610x; 1.0143x over previous
//
#include <hip/hip_runtime.h>
#include <hip/hip_bf16.h>
#include <math.h>

#define FEAT 1040
#define NHEAD 8
#define DHEAD 130
#define NLAYER 3
#define NGRAPH 64
#define NEG_SLOPE 0.2f
#define BN_EPS 1e-5f
#define KP 1056   // FEAT padded to multiple of 32 (K of GEMM)
#define NP 1152   // FEAT padded to multiple of 128; cols 1040..1055 = wa_src/wa_dst
#define NKT (KP / 32)   // 33 K-tiles

typedef float floatx4 __attribute__((ext_vector_type(4)));
typedef short shortx8 __attribute__((ext_vector_type(8)));

__device__ __forceinline__ short f2bf(float f) {
    unsigned u = __float_as_uint(f);
    u += 0x7fff + ((u >> 16) & 1);   // round-to-nearest-even
    return (short)(u >> 16);
}
__device__ __forceinline__ float bf2f(short b) {
    return __uint_as_float(((unsigned)(unsigned short)b) << 16);
}

__device__ __forceinline__ void async16(const void* g, void* l) {
    __builtin_amdgcn_global_load_lds(
        (const __attribute__((address_space(1))) unsigned int*)g,
        (__attribute__((address_space(3))) unsigned int*)l, 16, 0, 0);
}

// ---------------- bf16 MFMA GEMM ----------------
// 3-buffer LDS ring, prefetch distance 2, counted s_waitcnt vmcnt(4).
// Epilogue: C-tile staged in LDS (stride 136 to dodge bank conflicts, overlaid
// on the staging buffers) then written with coalesced 16-B stores (8/thread)
// instead of 64 scalar 2-B scattered stores.
__global__ __launch_bounds__(256) void gemm_mfma(const short* __restrict__ A,
                                                 const short* __restrict__ Bt,
                                                 short* __restrict__ xh_bf,
                                                 float* __restrict__ asrc,
                                                 float* __restrict__ adst,
                                                 int M, int MT) {
    const int lid = blockIdx.x;
    const int g = lid / 72, r = lid % 72;
    const int bmi = g * 8 + (r & 7);
    const int bni = r >> 3;
    if (bmi >= MT) return;
    const int bm = bmi * 128;
    const int bn = bni * 128;

    __shared__ short lds[24576];   // 48 KB: As[3][4096] | Bs[3][4096]; epilogue reuses as C
    short (*As)[4096] = (short (*)[4096])lds;
    short (*Bs)[4096] = (short (*)[4096])&lds[12288];
    short* Cs = lds;               // 128*136 = 17408 shorts (34.8 KB) for epilogue

    const int tid = threadIdx.x;
    const int lane = tid & 63;
    const int w = tid >> 6;
    const int wm = (w & 1) * 64;
    const int wn = (w >> 1) * 64;

    const int tt0 = tid, tt1 = 256 + tid;
    const int row0 = ((tt0 >> 6) << 4) | (tt0 & 15);
    const int col0 = ((tt0 >> 4) & 3) * 8;
    const int row1 = ((tt1 >> 6) << 4) | (tt1 & 15);
    const int col1 = ((tt1 >> 4) & 3) * 8;

    const short* gA0 = A + (size_t)(bm + row0) * KP + col0;
    const short* gA1 = A + (size_t)(bm + row1) * KP + col1;
    const short* gB0 = Bt + (size_t)(bn + row0) * KP + col0;
    const short* gB1 = Bt + (size_t)(bn + row1) * KP + col1;

    const int fr = lane & 15;
    const int kq = lane >> 4;

    floatx4 acc[4][4];
#pragma unroll
    for (int i = 0; i < 4; i++)
#pragma unroll
        for (int j = 0; j < 4; j++) acc[i][j] = (floatx4){0.f, 0.f, 0.f, 0.f};

    // prologue: stage tiles 0 and 1 (8 loads/thread in flight)
    async16(gA0, &As[0][tt0 * 8]);
    async16(gA1, &As[0][tt1 * 8]);
    async16(gB0, &Bs[0][tt0 * 8]);
    async16(gB1, &Bs[0][tt1 * 8]);
    async16(gA0 + 32, &As[1][tt0 * 8]);
    async16(gA1 + 32, &As[1][tt1 * 8]);
    async16(gB0 + 32, &Bs[1][tt0 * 8]);
    async16(gB1 + 32, &Bs[1][tt1 * 8]);

    int cur = 0;
    for (int it = 0; it < NKT; ++it) {
        if (it == NKT - 1) {
            asm volatile("s_waitcnt vmcnt(0)" ::: "memory");
        } else {
            asm volatile("s_waitcnt vmcnt(4)" ::: "memory");
        }
        __builtin_amdgcn_s_barrier();
        __builtin_amdgcn_sched_barrier(0);
        if (it + 2 < NKT) {
            int pf = cur + 2; if (pf >= 3) pf -= 3;
            const int kp = (it + 2) * 32;
            async16(gA0 + kp, &As[pf][tt0 * 8]);
            async16(gA1 + kp, &As[pf][tt1 * 8]);
            async16(gB0 + kp, &Bs[pf][tt0 * 8]);
            async16(gB1 + kp, &Bs[pf][tt1 * 8]);
        }
        shortx8 af[4], bfr[4];
#pragma unroll
        for (int i = 0; i < 4; i++) {
            af[i]  = *(const shortx8*)&As[cur][((wm >> 4) + i) * 512 + kq * 128 + fr * 8];
            bfr[i] = *(const shortx8*)&Bs[cur][((wn >> 4) + i) * 512 + kq * 128 + fr * 8];
        }
#pragma unroll
        for (int i = 0; i < 4; i++)
#pragma unroll
            for (int j = 0; j < 4; j++)
                acc[i][j] = __builtin_amdgcn_mfma_f32_16x16x32_bf16(af[i], bfr[j], acc[i][j], 0, 0, 0);
        cur = (cur == 2) ? 0 : cur + 1;
    }

    const int rbase = (lane >> 4) * 4;
    const int ccol = lane & 15;

    if (bni < 8) {
        // all 128 cols are valid xh cols (bn+128 <= 1024 < FEAT)
        __syncthreads();   // all waves done reading As/Bs before overlay
#pragma unroll
        for (int j = 0; j < 4; j++)
#pragma unroll
            for (int i = 0; i < 4; i++) {
                int rl = wm + i * 16 + rbase;
                int cl = wn + j * 16 + ccol;
#pragma unroll
                for (int r2 = 0; r2 < 4; r2++)
                    Cs[(rl + r2) * 136 + cl] = f2bf(acc[i][j][r2]);
            }
        __syncthreads();
        const int srow = tid >> 1, shalf = tid & 1;
        const int grow = bm + srow;
        if (grow < M) {
            const short* src = &Cs[srow * 136 + shalf * 64];
            short* dst = xh_bf + (size_t)grow * FEAT + bn + shalf * 64;
#pragma unroll
            for (int c8 = 0; c8 < 8; c8++)
                *(shortx8*)(dst + c8 * 8) = *(const shortx8*)(src + c8 * 8);
        }
    } else {
        // special tile: 16 xh cols + asrc/adst fp32 cols; old exact path
#pragma unroll
        for (int j = 0; j < 4; j++) {
            int colbase = bn + wn + j * 16;
            if (colbase < FEAT) {
                int col = colbase + ccol;
#pragma unroll
                for (int i = 0; i < 4; i++)
#pragma unroll
                    for (int r2 = 0; r2 < 4; r2++) {
                        int row = bm + wm + i * 16 + rbase + r2;
                        if (row < M) xh_bf[(size_t)row * FEAT + col] = f2bf(acc[i][j][r2]);
                    }
            } else if (colbase == FEAT) {
                int c = ccol;
                float* tgt = (c < 8) ? asrc : adst;
                int h = c & 7;
#pragma unroll
                for (int i = 0; i < 4; i++)
#pragma unroll
                    for (int r2 = 0; r2 < 4; r2++) {
                        int row = bm + wm + i * 16 + rbase + r2;
                        if (row < M) tgt[(size_t)row * NHEAD + h] = acc[i][j][r2];
                    }
            }
        }
    }
}

// ---------------- conversions / padding ----------------
__global__ void conv_x_bf(const float* __restrict__ x, short* __restrict__ out, int N) {
    int idx = blockIdx.x * 256 + threadIdx.x;   // index of 4-elem group
    int total = N * (FEAT / 4);
    if (idx >= total) return;
    int r = idx / (FEAT / 4), c4 = idx - r * (FEAT / 4);
    float4 v = *(const float4*)(x + (size_t)r * FEAT + c4 * 4);
    ushort4 o;
    o.x = (unsigned short)f2bf(v.x);
    o.y = (unsigned short)f2bf(v.y);
    o.z = (unsigned short)f2bf(v.z);
    o.w = (unsigned short)f2bf(v.w);
    *(ushort4*)(out + (size_t)r * KP + c4 * 4) = o;
}

__global__ void pad_bf(short* __restrict__ buf, int Mvalid) {
    int r = blockIdx.x;
    short* row = buf + (size_t)r * KP;
    if (r < Mvalid) {
        if (threadIdx.x < KP - FEAT) row[FEAT + threadIdx.x] = 0;
    } else {
        for (int c = threadIdx.x; c < KP; c += 64) row[c] = 0;
    }
}

__global__ void transpose_w(const float* __restrict__ Wl, short* __restrict__ Bt) {
    __shared__ float t[32][33];
    int kb = blockIdx.x * 32, nb = blockIdx.y * 32;
    int tx = threadIdx.x & 31, ty = threadIdx.x >> 5;
#pragma unroll
    for (int i = 0; i < 4; i++) {
        int k = kb + ty + i * 8, n = nb + tx;
        t[ty + i * 8][tx] = (k < FEAT && n < FEAT) ? Wl[(size_t)k * FEAT + n] : 0.f;
    }
    __syncthreads();
#pragma unroll
    for (int i = 0; i < 4; i++) {
        int n = nb + ty + i * 8, k = kb + tx;
        if (n < FEAT && k < FEAT) Bt[(size_t)n * KP + k] = f2bf(t[tx][ty + i * 8]);
    }
}

__global__ void wa_kernel(const float* __restrict__ W, const float* __restrict__ a_s,
                          const float* __restrict__ a_d, short* __restrict__ Bt3) {
    int t = blockIdx.x * 256 + threadIdx.x;
    if (t >= NLAYER * FEAT * NHEAD) return;
    int h = t & 7;
    int f = (t >> 3) % FEAT;
    int l = t / (FEAT * NHEAD);
    const float* wrow = W + (((size_t)l * FEAT + f) * NHEAD + h) * DHEAD;
    const float* as = a_s + ((size_t)l * NHEAD + h) * DHEAD;
    const float* ad = a_d + ((size_t)l * NHEAD + h) * DHEAD;
    float ws = 0.f, wd = 0.f;
    for (int d = 0; d < DHEAD; d++) {
        float wv = wrow[d];
        ws += wv * as[d];
        wd += wv * ad[d];
    }
    short* base = Bt3 + (size_t)l * NP * KP;
    base[(size_t)(FEAT + h) * KP + f] = f2bf(ws);
    base[(size_t)(FEAT + 8 + h) * KP + f] = f2bf(wd);
}

// ---------------- graph preprocessing ----------------
__global__ void build_edges(const int* __restrict__ ei, int E, int N,
                            int* __restrict__ src2, int* __restrict__ dst2,
                            int* __restrict__ deg) {
    int e = blockIdx.x * 256 + threadIdx.x;
    int E2 = E + N;
    if (e >= E2) return;
    int s, d;
    if (e < E) { s = ei[e]; d = ei[E + e]; }
    else       { s = e - E; d = e - E; }
    src2[e] = s;
    dst2[e] = d;
    atomicAdd(&deg[d], 1);
}

__global__ void scan_kernel(const int* __restrict__ deg, int* __restrict__ off,
                            int* __restrict__ cursor, int N) {
    __shared__ int wsum[16];
    __shared__ int carry_s;
    int tid = threadIdx.x;
    int lane = tid & 63, wid = tid >> 6;
    if (tid == 0) carry_s = 0;
    __syncthreads();
    for (int base = 0; base < N; base += 1024) {
        int i = base + tid;
        int v = (i < N) ? deg[i] : 0;
        int incl = v;
#pragma unroll
        for (int o = 1; o < 64; o <<= 1) {
            int u = __shfl_up(incl, o);
            if (lane >= o) incl += u;
        }
        if (lane == 63) wsum[wid] = incl;
        __syncthreads();
        if (wid == 0) {
            int wv = (lane < 16) ? wsum[lane] : 0;
            int wincl = wv;
#pragma unroll
            for (int o = 1; o < 16; o <<= 1) {
                int u = __shfl_up(wincl, o);
                if (lane >= o) wincl += u;
            }
            if (lane < 16) wsum[lane] = wincl - wv;
        }
        __syncthreads();
        int excl = carry_s + wsum[wid] + incl - v;
        if (i < N) { off[i] = excl; cursor[i] = excl; }
        int tot = 0;
        if (tid == 1023) tot = wsum[15] + incl;
        __syncthreads();
        if (tid == 1023) carry_s += tot;
        __syncthreads();
    }
    if (threadIdx.x == 0) off[N] = carry_s;
}

__global__ void scatter_k(const int* __restrict__ src2, const int* __restrict__ dst2,
                          int* __restrict__ cursor, int* __restrict__ ssrc, int E2) {
    int e = blockIdx.x * 256 + threadIdx.x;
    if (e >= E2) return;
    int d = dst2[e];
    int pos = atomicAdd(&cursor[d], 1);
    ssrc[pos] = src2[e];
}

__global__ void gstart_k(const int* __restrict__ batch, int* __restrict__ gstart, int N) {
    int n = blockIdx.x * 256 + threadIdx.x;
    if (n >= N) return;
    int b = batch[n];
    if (n == 0) {
        for (int g = 0; g <= b; g++) gstart[g] = 0;
    } else {
        int pb = batch[n - 1];
        for (int g = pb + 1; g <= b; g++) gstart[g] = n;
    }
    if (n == N - 1) {
        for (int g = b + 1; g <= NGRAPH; g++) gstart[g] = N;
    }
}

// ---- leaky-relu + segment softmax, ONE PASS (no max subtraction) ------------
__global__ void att_softmax(const int* __restrict__ off, const int* __restrict__ ssrc,
                            const float* __restrict__ asrc, const float* __restrict__ adst,
                            float* __restrict__ p, float* __restrict__ dinv, int N) {
    int t = blockIdx.x * 256 + threadIdx.x;
    if (t >= N * NHEAD) return;
    int n = t >> 3, h = t & 7;
    int s = off[n], e = off[n + 1];
    float ad = adst[(size_t)n * NHEAD + h];
    float sum = 0.f;
    int j = s;
    for (; j + 4 <= e; j += 4) {
        float v0 = asrc[(size_t)ssrc[j] * NHEAD + h] + ad;
        float v1 = asrc[(size_t)ssrc[j + 1] * NHEAD + h] + ad;
        float v2 = asrc[(size_t)ssrc[j + 2] * NHEAD + h] + ad;
        float v3 = asrc[(size_t)ssrc[j + 3] * NHEAD + h] + ad;
        v0 = (v0 > 0.f) ? v0 : NEG_SLOPE * v0;
        v1 = (v1 > 0.f) ? v1 : NEG_SLOPE * v1;
        v2 = (v2 > 0.f) ? v2 : NEG_SLOPE * v2;
        v3 = (v3 > 0.f) ? v3 : NEG_SLOPE * v3;
        float e0 = __expf(fminf(v0, 60.f)), e1 = __expf(fminf(v1, 60.f));
        float e2 = __expf(fminf(v2, 60.f)), e3 = __expf(fminf(v3, 60.f));
        p[(size_t)j * NHEAD + h] = e0;
        p[(size_t)(j + 1) * NHEAD + h] = e1;
        p[(size_t)(j + 2) * NHEAD + h] = e2;
        p[(size_t)(j + 3) * NHEAD + h] = e3;
        sum += (e0 + e1) + (e2 + e3);
    }
    for (; j < e; j++) {
        float v = asrc[(size_t)ssrc[j] * NHEAD + h] + ad;
        v = (v > 0.f) ? v : NEG_SLOPE * v;
        float ex = __expf(fminf(v, 60.f));
        p[(size_t)j * NHEAD + h] = ex;
        sum += ex;
    }
    dinv[(size_t)n * NHEAD + h] = 1.0f / sum;
}

// ---------------- aggregation + BN + ReLU (softmax denom folded in) ----------
// R2 structure (1 node/block, 320 thr, 260 active, 8-B gathers, 2 p-loads/edge)
__global__ __launch_bounds__(320) void aggregate(
    const short* __restrict__ xh_bf, const float* __restrict__ p,
    const float* __restrict__ dinv,
    const int* __restrict__ off, const int* __restrict__ ssrc,
    const float* __restrict__ prev_f,     // fp32 residual (layer 1: x) or null
    const short* __restrict__ prev_bf,    // bf16 residual (layer 2: hA_bf) or null
    const float* __restrict__ b_att, const float* __restrict__ gamma,
    const float* __restrict__ beta, const float* __restrict__ mean,
    const float* __restrict__ var,
    short* __restrict__ hout_bf, int N) {
    int n = blockIdx.x;
    int t = threadIdx.x;
    if (t >= 260) return;
    int f0 = t * 4;
    int s = off[n], e = off[n + 1];
    const int hA = f0 / DHEAD;
    const int hB = (f0 + 3) / DHEAD;     // == hA for 126/130 of threads
    const int sp = hB * DHEAD - f0;      // feats i<sp use head hA (i in 0..3)
    float acc[4] = {0.f, 0.f, 0.f, 0.f};

    int j = s;
    for (; j + 8 <= e; j += 8) {
        int sj[8];
        ushort4 v[8];
#pragma unroll
        for (int u = 0; u < 8; u++) sj[u] = ssrc[j + u];
#pragma unroll
        for (int u = 0; u < 8; u++) v[u] = *(const ushort4*)(xh_bf + (size_t)sj[u] * FEAT + f0);
#pragma unroll
        for (int u = 0; u < 8; u++) {
            const float* pj = p + (size_t)(j + u) * NHEAD;
            float pa = pj[hA], pb = pj[hB];
            acc[0] += ((0 < sp) ? pa : pb) * bf2f((short)v[u].x);
            acc[1] += ((1 < sp) ? pa : pb) * bf2f((short)v[u].y);
            acc[2] += ((2 < sp) ? pa : pb) * bf2f((short)v[u].z);
            acc[3] += ((3 < sp) ? pa : pb) * bf2f((short)v[u].w);
        }
    }
    for (; j + 4 <= e; j += 4) {
        int sj[4];
        ushort4 v[4];
#pragma unroll
        for (int u = 0; u < 4; u++) sj[u] = ssrc[j + u];
#pragma unroll
        for (int u = 0; u < 4; u++) v[u] = *(const ushort4*)(xh_bf + (size_t)sj[u] * FEAT + f0);
#pragma unroll
        for (int u = 0; u < 4; u++) {
            const float* pj = p + (size_t)(j + u) * NHEAD;
            float pa = pj[hA], pb = pj[hB];
            acc[0] += ((0 < sp) ? pa : pb) * bf2f((short)v[u].x);
            acc[1] += ((1 < sp) ? pa : pb) * bf2f((short)v[u].y);
            acc[2] += ((2 < sp) ? pa : pb) * bf2f((short)v[u].z);
            acc[3] += ((3 < sp) ? pa : pb) * bf2f((short)v[u].w);
        }
    }
    for (; j < e; j++) {
        int src = ssrc[j];
        ushort4 v = *(const ushort4*)(xh_bf + (size_t)src * FEAT + f0);
        const float* pj = p + (size_t)j * NHEAD;
        float pa = pj[hA], pb = pj[hB];
        acc[0] += ((0 < sp) ? pa : pb) * bf2f((short)v.x);
        acc[1] += ((1 < sp) ? pa : pb) * bf2f((short)v.y);
        acc[2] += ((2 < sp) ? pa : pb) * bf2f((short)v.z);
        acc[3] += ((3 < sp) ? pa : pb) * bf2f((short)v.w);
    }

    // fold softmax denominator (per head)
    float da = dinv[(size_t)n * NHEAD + hA];
    float db = dinv[(size_t)n * NHEAD + hB];
    acc[0] *= (0 < sp) ? da : db;
    acc[1] *= (1 < sp) ? da : db;
    acc[2] *= (2 < sp) ? da : db;
    acc[3] *= (3 < sp) ? da : db;

    float4 bv = *(const float4*)(b_att + f0);
    float4 gv = *(const float4*)(gamma + f0);
    float4 be = *(const float4*)(beta + f0);
    float4 mv = *(const float4*)(mean + f0);
    float4 vv = *(const float4*)(var + f0);
    float z[4] = {acc[0] + bv.x, acc[1] + bv.y, acc[2] + bv.z, acc[3] + bv.w};
    if (prev_f) {
        float4 pv = *(const float4*)(prev_f + (size_t)n * FEAT + f0);
        z[0] += pv.x; z[1] += pv.y; z[2] += pv.z; z[3] += pv.w;
    }
    if (prev_bf) {
        ushort4 pv = *(const ushort4*)(prev_bf + (size_t)n * KP + f0);
        z[0] += bf2f((short)pv.x); z[1] += bf2f((short)pv.y);
        z[2] += bf2f((short)pv.z); z[3] += bf2f((short)pv.w);
    }
    float g4[4] = {gv.x, gv.y, gv.z, gv.w};
    float b4[4] = {be.x, be.y, be.z, be.w};
    float m4[4] = {mv.x, mv.y, mv.z, mv.w};
    float v4[4] = {vv.x, vv.y, vv.z, vv.w};
    ushort4 o;
    unsigned short* op = (unsigned short*)&o;
#pragma unroll
    for (int i = 0; i < 4; i++) {
        float zz = (z[i] - m4[i]) * rsqrtf(v4[i] + BN_EPS) * g4[i] + b4[i];
        op[i] = (unsigned short)f2bf(fmaxf(zz, 0.f));
    }
    *(ushort4*)(hout_bf + (size_t)n * KP + f0) = o;
}

// ---------------- pooling over contiguous node ranges ----------------
__global__ __launch_bounds__(320) void pool_k(const short* __restrict__ h,
                                              const int* __restrict__ gstart,
                                              float* __restrict__ pooled) {
    int g = blockIdx.x;
    int t = threadIdx.x;
    if (t >= 260) return;
    int f0 = t * 4;
    int s = gstart[g], e = gstart[g + 1];
    float acc[4] = {0.f, 0.f, 0.f, 0.f};
    int n = s;
    for (; n + 4 <= e; n += 4) {
        ushort4 v0 = *(const ushort4*)(h + (size_t)n * KP + f0);
        ushort4 v1 = *(const ushort4*)(h + (size_t)(n + 1) * KP + f0);
        ushort4 v2 = *(const ushort4*)(h + (size_t)(n + 2) * KP + f0);
        ushort4 v3 = *(const ushort4*)(h + (size_t)(n + 3) * KP + f0);
        acc[0] += bf2f((short)v0.x) + bf2f((short)v1.x) + bf2f((short)v2.x) + bf2f((short)v3.x);
        acc[1] += bf2f((short)v0.y) + bf2f((short)v1.y) + bf2f((short)v2.y) + bf2f((short)v3.y);
        acc[2] += bf2f((short)v0.z) + bf2f((short)v1.z) + bf2f((short)v2.z) + bf2f((short)v3.z);
        acc[3] += bf2f((short)v0.w) + bf2f((short)v1.w) + bf2f((short)v2.w) + bf2f((short)v3.w);
    }
    for (; n < e; n++) {
        ushort4 v = *(const ushort4*)(h + (size_t)n * KP + f0);
        acc[0] += bf2f((short)v.x);
        acc[1] += bf2f((short)v.y);
        acc[2] += bf2f((short)v.z);
        acc[3] += bf2f((short)v.w);
    }
    *(float4*)(pooled + (size_t)g * FEAT + f0) = make_float4(acc[0], acc[1], acc[2], acc[3]);
}

__global__ void final_k(const float* __restrict__ pooled, const int* __restrict__ gstart,
                        const float* __restrict__ W_out, const float* __restrict__ b_out,
                        float* __restrict__ out) {
    int g = blockIdx.x >> 1, c = blockIdx.x & 1;
    int lane = threadIdx.x;  // 64
    float ssum = 0.f;
    for (int f = lane; f < FEAT; f += 64) ssum += pooled[(size_t)g * FEAT + f] * W_out[f * 2 + c];
#pragma unroll
    for (int o = 1; o < 64; o <<= 1) ssum += __shfl_xor(ssum, o);
    if (lane == 0) {
        float cnt = (float)(gstart[g + 1] - gstart[g]);
        float inv = 1.0f / fmaxf(cnt, 1.0f);
        out[g * 2 + c] = ssum * inv + b_out[c];
    }
}

// ---------------- launch ----------------
extern "C" void kernel_launch(void* const* d_in, const int* in_sizes, int n_in,
                              void* d_out, int out_size, void* d_ws, size_t ws_size,
                              hipStream_t stream) {
    const float* x       = (const float*)d_in[0];
    const int*   ei      = (const int*)d_in[1];
    const int*   batch   = (const int*)d_in[2];
    const float* W       = (const float*)d_in[3];
    const float* a_src   = (const float*)d_in[4];
    const float* a_dst   = (const float*)d_in[5];
    const float* b_att   = (const float*)d_in[6];
    const float* gamma   = (const float*)d_in[7];
    const float* beta    = (const float*)d_in[8];
    const float* r_mean  = (const float*)d_in[9];
    const float* r_var   = (const float*)d_in[10];
    const float* W_out   = (const float*)d_in[11];
    const float* b_out   = (const float*)d_in[12];
    float* out = (float*)d_out;

    const int N = in_sizes[0] / FEAT;
    const int E = in_sizes[1] / 2;
    const int E2 = E + N;
    const int MT = (N + 127) / 128;
    const int Mp = MT * 128;
    const int MTpad = ((MT + 7) / 8) * 8;

    char* w = (char*)d_ws;
    auto alloc = [&](size_t bytes) {
        void* pp = (void*)w;
        w += (bytes + 255) & ~(size_t)255;
        return pp;
    };
    short* xh_bf  = (short*)alloc((size_t)N * FEAT * 2);
    short* x_bf   = (short*)alloc((size_t)Mp * KP * 2);   // layer-0 A; reused as layer-3 h
    short* hA_bf  = (short*)alloc((size_t)Mp * KP * 2);
    short* hB_bf  = (short*)alloc((size_t)Mp * KP * 2);
    short* Bt3    = (short*)alloc((size_t)NLAYER * NP * KP * 2);
    float* p      = (float*)alloc((size_t)E2 * NHEAD * 4);
    float* asrc   = (float*)alloc((size_t)N * NHEAD * 4);
    float* adst   = (float*)alloc((size_t)N * NHEAD * 4);
    float* dinv   = (float*)alloc((size_t)N * NHEAD * 4);
    int*   src2   = (int*)alloc((size_t)E2 * 4);
    int*   dst2   = (int*)alloc((size_t)E2 * 4);
    int*   ssrc   = (int*)alloc((size_t)E2 * 4);
    int*   deg    = (int*)alloc((size_t)N * 4);
    int*   off    = (int*)alloc((size_t)(N + 1) * 4);
    int*   cursor = (int*)alloc((size_t)N * 4);
    int*   gstart = (int*)alloc((size_t)(NGRAPH + 1) * 4);
    float* pooled = (float*)alloc((size_t)NGRAPH * FEAT * 4);

    hipMemsetAsync(deg, 0, (size_t)N * 4, stream);
    hipMemsetAsync(Bt3, 0, (size_t)NLAYER * NP * KP * 2, stream);

    conv_x_bf<<<(N * (FEAT / 4) + 255) / 256, 256, 0, stream>>>(x, x_bf, N);
    pad_bf<<<Mp, 64, 0, stream>>>(x_bf, N);
    pad_bf<<<Mp, 64, 0, stream>>>(hA_bf, N);
    pad_bf<<<Mp, 64, 0, stream>>>(hB_bf, N);
    dim3 tgrid((FEAT + 31) / 32, (FEAT + 31) / 32);
    for (int l = 0; l < NLAYER; l++)
        transpose_w<<<tgrid, 256, 0, stream>>>(W + (size_t)l * FEAT * FEAT,
                                               Bt3 + (size_t)l * NP * KP);
    wa_kernel<<<(NLAYER * FEAT * NHEAD + 255) / 256, 256, 0, stream>>>(W, a_src, a_dst, Bt3);

    build_edges<<<(E2 + 255) / 256, 256, 0, stream>>>(ei, E, N, src2, dst2, deg);
    scan_kernel<<<1, 1024, 0, stream>>>(deg, off, cursor, N);
    scatter_k<<<(E2 + 255) / 256, 256, 0, stream>>>(src2, dst2, cursor, ssrc, E2);
    gstart_k<<<(N + 255) / 256, 256, 0, stream>>>(batch, gstart, N);

    const short* hin[NLAYER]     = {x_bf, hA_bf, hB_bf};
    const float* prevf[NLAYER]   = {nullptr, x, nullptr};
    const short* prevbf[NLAYER]  = {nullptr, nullptr, hA_bf};
    short* houtl[NLAYER]         = {hA_bf, hB_bf, x_bf};

    for (int l = 0; l < NLAYER; l++) {
        gemm_mfma<<<MTpad * 9, 256, 0, stream>>>(hin[l], Bt3 + (size_t)l * NP * KP,
                                                 xh_bf, asrc, adst, N, MT);
        att_softmax<<<(N * NHEAD + 255) / 256, 256, 0, stream>>>(off, ssrc, asrc, adst, p, dinv, N);
        aggregate<<<N, 320, 0, stream>>>(xh_bf, p, dinv, off, ssrc, prevf[l], prevbf[l],
                                         b_att + l * FEAT, gamma + l * FEAT, beta + l * FEAT,
                                         r_mean + l * FEAT, r_var + l * FEAT,
                                         houtl[l], N);
    }

    pool_k<<<NGRAPH, 320, 0, stream>>>(x_bf, gstart, pooled);
    final_k<<<NGRAPH * 2, 64, 0, stream>>>(pooled, gstart, W_out, b_out, out);
}

// Round 7
// 1056.055 us; speedup vs baseline: 1.3158x; 1.0434x over previous
//
#include <hip/hip_runtime.h>
#include <hip/hip_bf16.h>
#include <math.h>

#define FEAT 1040
#define NHEAD 8
#define DHEAD 130
#define NLAYER 3
#define NGRAPH 64
#define NEG_SLOPE 0.2f
#define BN_EPS 1e-5f
#define KP 1056   // FEAT padded to multiple of 32 (K of GEMM)
#define NP 1152   // FEAT padded to multiple of 128; cols 1040..1055 = wa_src/wa_dst
#define NKT (KP / 32)   // 33 K-tiles

typedef float floatx4 __attribute__((ext_vector_type(4)));
typedef short shortx8 __attribute__((ext_vector_type(8)));

__device__ __forceinline__ short f2bf(float f) {
    unsigned u = __float_as_uint(f);
    u += 0x7fff + ((u >> 16) & 1);   // round-to-nearest-even
    return (short)(u >> 16);
}
__device__ __forceinline__ float bf2f(short b) {
    return __uint_as_float(((unsigned)(unsigned short)b) << 16);
}

__device__ __forceinline__ void async16(const void* g, void* l) {
    __builtin_amdgcn_global_load_lds(
        (const __attribute__((address_space(1))) unsigned int*)g,
        (__attribute__((address_space(3))) unsigned int*)l, 16, 0, 0);
}

// ---------------- bf16 MFMA GEMM ----------------
// 3-buffer LDS ring, prefetch distance 2, counted s_waitcnt vmcnt(4).
// Coalesced epilogue via LDS C-stage (stride 136).
__global__ __launch_bounds__(256) void gemm_mfma(const short* __restrict__ A,
                                                 const short* __restrict__ Bt,
                                                 short* __restrict__ xh_bf,
                                                 float* __restrict__ asrc,
                                                 float* __restrict__ adst,
                                                 int M, int MT) {
    const int lid = blockIdx.x;
    const int g = lid / 72, r = lid % 72;
    const int bmi = g * 8 + (r & 7);
    const int bni = r >> 3;
    if (bmi >= MT) return;
    const int bm = bmi * 128;
    const int bn = bni * 128;

    __shared__ short lds[24576];   // 48 KB: As[3][4096] | Bs[3][4096]; epilogue reuses as C
    short (*As)[4096] = (short (*)[4096])lds;
    short (*Bs)[4096] = (short (*)[4096])&lds[12288];
    short* Cs = lds;               // 128*136 shorts for epilogue

    const int tid = threadIdx.x;
    const int lane = tid & 63;
    const int w = tid >> 6;
    const int wm = (w & 1) * 64;
    const int wn = (w >> 1) * 64;

    const int tt0 = tid, tt1 = 256 + tid;
    const int row0 = ((tt0 >> 6) << 4) | (tt0 & 15);
    const int col0 = ((tt0 >> 4) & 3) * 8;
    const int row1 = ((tt1 >> 6) << 4) | (tt1 & 15);
    const int col1 = ((tt1 >> 4) & 3) * 8;

    const short* gA0 = A + (size_t)(bm + row0) * KP + col0;
    const short* gA1 = A + (size_t)(bm + row1) * KP + col1;
    const short* gB0 = Bt + (size_t)(bn + row0) * KP + col0;
    const short* gB1 = Bt + (size_t)(bn + row1) * KP + col1;

    const int fr = lane & 15;
    const int kq = lane >> 4;

    floatx4 acc[4][4];
#pragma unroll
    for (int i = 0; i < 4; i++)
#pragma unroll
        for (int j = 0; j < 4; j++) acc[i][j] = (floatx4){0.f, 0.f, 0.f, 0.f};

    async16(gA0, &As[0][tt0 * 8]);
    async16(gA1, &As[0][tt1 * 8]);
    async16(gB0, &Bs[0][tt0 * 8]);
    async16(gB1, &Bs[0][tt1 * 8]);
    async16(gA0 + 32, &As[1][tt0 * 8]);
    async16(gA1 + 32, &As[1][tt1 * 8]);
    async16(gB0 + 32, &Bs[1][tt0 * 8]);
    async16(gB1 + 32, &Bs[1][tt1 * 8]);

    int cur = 0;
    for (int it = 0; it < NKT; ++it) {
        if (it == NKT - 1) {
            asm volatile("s_waitcnt vmcnt(0)" ::: "memory");
        } else {
            asm volatile("s_waitcnt vmcnt(4)" ::: "memory");
        }
        __builtin_amdgcn_s_barrier();
        __builtin_amdgcn_sched_barrier(0);
        if (it + 2 < NKT) {
            int pf = cur + 2; if (pf >= 3) pf -= 3;
            const int kp = (it + 2) * 32;
            async16(gA0 + kp, &As[pf][tt0 * 8]);
            async16(gA1 + kp, &As[pf][tt1 * 8]);
            async16(gB0 + kp, &Bs[pf][tt0 * 8]);
            async16(gB1 + kp, &Bs[pf][tt1 * 8]);
        }
        shortx8 af[4], bfr[4];
#pragma unroll
        for (int i = 0; i < 4; i++) {
            af[i]  = *(const shortx8*)&As[cur][((wm >> 4) + i) * 512 + kq * 128 + fr * 8];
            bfr[i] = *(const shortx8*)&Bs[cur][((wn >> 4) + i) * 512 + kq * 128 + fr * 8];
        }
#pragma unroll
        for (int i = 0; i < 4; i++)
#pragma unroll
            for (int j = 0; j < 4; j++)
                acc[i][j] = __builtin_amdgcn_mfma_f32_16x16x32_bf16(af[i], bfr[j], acc[i][j], 0, 0, 0);
        cur = (cur == 2) ? 0 : cur + 1;
    }

    const int rbase = (lane >> 4) * 4;
    const int ccol = lane & 15;

    if (bni < 8) {
        __syncthreads();
#pragma unroll
        for (int j = 0; j < 4; j++)
#pragma unroll
            for (int i = 0; i < 4; i++) {
                int rl = wm + i * 16 + rbase;
                int cl = wn + j * 16 + ccol;
#pragma unroll
                for (int r2 = 0; r2 < 4; r2++)
                    Cs[(rl + r2) * 136 + cl] = f2bf(acc[i][j][r2]);
            }
        __syncthreads();
        const int srow = tid >> 1, shalf = tid & 1;
        const int grow = bm + srow;
        if (grow < M) {
            const short* src = &Cs[srow * 136 + shalf * 64];
            short* dst = xh_bf + (size_t)grow * FEAT + bn + shalf * 64;
#pragma unroll
            for (int c8 = 0; c8 < 8; c8++)
                *(shortx8*)(dst + c8 * 8) = *(const shortx8*)(src + c8 * 8);
        }
    } else {
#pragma unroll
        for (int j = 0; j < 4; j++) {
            int colbase = bn + wn + j * 16;
            if (colbase < FEAT) {
                int col = colbase + ccol;
#pragma unroll
                for (int i = 0; i < 4; i++)
#pragma unroll
                    for (int r2 = 0; r2 < 4; r2++) {
                        int row = bm + wm + i * 16 + rbase + r2;
                        if (row < M) xh_bf[(size_t)row * FEAT + col] = f2bf(acc[i][j][r2]);
                    }
            } else if (colbase == FEAT) {
                int c = ccol;
                float* tgt = (c < 8) ? asrc : adst;
                int h = c & 7;
#pragma unroll
                for (int i = 0; i < 4; i++)
#pragma unroll
                    for (int r2 = 0; r2 < 4; r2++) {
                        int row = bm + wm + i * 16 + rbase + r2;
                        if (row < M) tgt[(size_t)row * NHEAD + h] = acc[i][j][r2];
                    }
            }
        }
    }
}

// ---------------- conversions / padding ----------------
// fused: bf16 convert of x into padded x_bf, zeros for pad cols and pad rows
__global__ void conv_pad_x(const float* __restrict__ x, short* __restrict__ out,
                           int N, int Mp) {
    int idx = blockIdx.x * 256 + threadIdx.x;   // index of 8-elem group
    int total = Mp * (KP / 8);
    if (idx >= total) return;
    int r = idx / (KP / 8), c = (idx - r * (KP / 8)) * 8;
    shortx8 o = (shortx8){0, 0, 0, 0, 0, 0, 0, 0};
    if (r < N && c < FEAT) {   // FEAT % 8 == 0, so full group valid
        float4 v0 = *(const float4*)(x + (size_t)r * FEAT + c);
        float4 v1 = *(const float4*)(x + (size_t)r * FEAT + c + 4);
        o[0] = f2bf(v0.x); o[1] = f2bf(v0.y); o[2] = f2bf(v0.z); o[3] = f2bf(v0.w);
        o[4] = f2bf(v1.x); o[5] = f2bf(v1.y); o[6] = f2bf(v1.z); o[7] = f2bf(v1.w);
    }
    *(shortx8*)(out + (size_t)r * KP + c) = o;
}

__global__ void pad_bf(short* __restrict__ buf, int Mvalid) {
    int r = blockIdx.x;
    short* row = buf + (size_t)r * KP;
    if (r < Mvalid) {
        if (threadIdx.x < KP - FEAT) row[FEAT + threadIdx.x] = 0;
    } else {
        for (int c = threadIdx.x; c < KP; c += 64) row[c] = 0;
    }
}

// batched over layers via blockIdx.z
__global__ void transpose_w(const float* __restrict__ W, short* __restrict__ Bt3) {
    __shared__ float t[32][33];
    int l = blockIdx.z;
    const float* Wl = W + (size_t)l * FEAT * FEAT;
    short* Bt = Bt3 + (size_t)l * NP * KP;
    int kb = blockIdx.x * 32, nb = blockIdx.y * 32;
    int tx = threadIdx.x & 31, ty = threadIdx.x >> 5;
#pragma unroll
    for (int i = 0; i < 4; i++) {
        int k = kb + ty + i * 8, n = nb + tx;
        t[ty + i * 8][tx] = (k < FEAT && n < FEAT) ? Wl[(size_t)k * FEAT + n] : 0.f;
    }
    __syncthreads();
#pragma unroll
    for (int i = 0; i < 4; i++) {
        int n = nb + ty + i * 8, k = kb + tx;
        if (n < FEAT && k < FEAT) Bt[(size_t)n * KP + k] = f2bf(t[tx][ty + i * 8]);
    }
}

__global__ void wa_kernel(const float* __restrict__ W, const float* __restrict__ a_s,
                          const float* __restrict__ a_d, short* __restrict__ Bt3) {
    int t = blockIdx.x * 256 + threadIdx.x;
    if (t >= NLAYER * FEAT * NHEAD) return;
    int h = t & 7;
    int f = (t >> 3) % FEAT;
    int l = t / (FEAT * NHEAD);
    const float* wrow = W + (((size_t)l * FEAT + f) * NHEAD + h) * DHEAD;
    const float* as = a_s + ((size_t)l * NHEAD + h) * DHEAD;
    const float* ad = a_d + ((size_t)l * NHEAD + h) * DHEAD;
    float ws = 0.f, wd = 0.f;
    for (int d = 0; d < DHEAD; d++) {
        float wv = wrow[d];
        ws += wv * as[d];
        wd += wv * ad[d];
    }
    short* base = Bt3 + (size_t)l * NP * KP;
    base[(size_t)(FEAT + h) * KP + f] = f2bf(ws);
    base[(size_t)(FEAT + 8 + h) * KP + f] = f2bf(wd);
}

// ---------------- graph preprocessing ----------------
__global__ void build_edges(const int* __restrict__ ei, int E, int N,
                            int* __restrict__ src2, int* __restrict__ dst2,
                            int* __restrict__ deg) {
    int e = blockIdx.x * 256 + threadIdx.x;
    int E2 = E + N;
    if (e >= E2) return;
    int s, d;
    if (e < E) { s = ei[e]; d = ei[E + e]; }
    else       { s = e - E; d = e - E; }
    src2[e] = s;
    dst2[e] = d;
    atomicAdd(&deg[d], 1);
}

// ---- parallel 3-phase scan (replaces single-block serial scan) ----
__global__ void scan_part(const int* __restrict__ deg, int* __restrict__ off,
                          int* __restrict__ part, int N) {
    __shared__ int wsum[16];
    int tid = threadIdx.x;
    int i = blockIdx.x * 1024 + tid;
    int lane = tid & 63, wid = tid >> 6;
    int v = (i < N) ? deg[i] : 0;
    int incl = v;
#pragma unroll
    for (int o = 1; o < 64; o <<= 1) {
        int u = __shfl_up(incl, o);
        if (lane >= o) incl += u;
    }
    if (lane == 63) wsum[wid] = incl;
    __syncthreads();
    if (wid == 0) {
        int wv = (lane < 16) ? wsum[lane] : 0;
        int wincl = wv;
#pragma unroll
        for (int o = 1; o < 16; o <<= 1) {
            int u = __shfl_up(wincl, o);
            if (lane >= o) wincl += u;
        }
        if (lane < 16) wsum[lane] = wincl - wv;
    }
    __syncthreads();
    int excl = wsum[wid] + incl - v;
    if (i < N) off[i] = excl;              // block-local exclusive
    if (tid == 1023) part[blockIdx.x] = wsum[15] + incl;   // block total
}

__global__ void scan_carry(int* __restrict__ part, int* __restrict__ off,
                           int NB, int N) {
    int lane = threadIdx.x;   // 64
    int run = 0;
    for (int base = 0; base < NB; base += 64) {
        int idx = base + lane;
        int v = (idx < NB) ? part[idx] : 0;
        int incl = v;
#pragma unroll
        for (int o = 1; o < 64; o <<= 1) {
            int u = __shfl_up(incl, o);
            if (lane >= o) incl += u;
        }
        if (idx < NB) part[idx] = run + incl - v;   // exclusive carry
        run += __shfl(incl, 63);
    }
    if (lane == 0) off[N] = run;
}

__global__ void scan_add(const int* __restrict__ part, int* __restrict__ off,
                         int* __restrict__ cursor, int N) {
    int i = blockIdx.x * 256 + threadIdx.x;
    if (i >= N) return;
    int o = off[i] + part[i >> 10];
    off[i] = o;
    cursor[i] = o;
}

__global__ void scatter_k(const int* __restrict__ src2, const int* __restrict__ dst2,
                          int* __restrict__ cursor, int* __restrict__ ssrc, int E2) {
    int e = blockIdx.x * 256 + threadIdx.x;
    if (e >= E2) return;
    int d = dst2[e];
    int pos = atomicAdd(&cursor[d], 1);
    ssrc[pos] = src2[e];
}

__global__ void gstart_k(const int* __restrict__ batch, int* __restrict__ gstart, int N) {
    int n = blockIdx.x * 256 + threadIdx.x;
    if (n >= N) return;
    int b = batch[n];
    if (n == 0) {
        for (int g = 0; g <= b; g++) gstart[g] = 0;
    } else {
        int pb = batch[n - 1];
        for (int g = pb + 1; g <= b; g++) gstart[g] = n;
    }
    if (n == N - 1) {
        for (int g = b + 1; g <= NGRAPH; g++) gstart[g] = N;
    }
}

// ---- leaky-relu + segment softmax, ONE PASS (no max subtraction) ------------
__global__ void att_softmax(const int* __restrict__ off, const int* __restrict__ ssrc,
                            const float* __restrict__ asrc, const float* __restrict__ adst,
                            float* __restrict__ p, float* __restrict__ dinv, int N) {
    int t = blockIdx.x * 256 + threadIdx.x;
    if (t >= N * NHEAD) return;
    int n = t >> 3, h = t & 7;
    int s = off[n], e = off[n + 1];
    float ad = adst[(size_t)n * NHEAD + h];
    float sum = 0.f;
    int j = s;
    for (; j + 4 <= e; j += 4) {
        float v0 = asrc[(size_t)ssrc[j] * NHEAD + h] + ad;
        float v1 = asrc[(size_t)ssrc[j + 1] * NHEAD + h] + ad;
        float v2 = asrc[(size_t)ssrc[j + 2] * NHEAD + h] + ad;
        float v3 = asrc[(size_t)ssrc[j + 3] * NHEAD + h] + ad;
        v0 = (v0 > 0.f) ? v0 : NEG_SLOPE * v0;
        v1 = (v1 > 0.f) ? v1 : NEG_SLOPE * v1;
        v2 = (v2 > 0.f) ? v2 : NEG_SLOPE * v2;
        v3 = (v3 > 0.f) ? v3 : NEG_SLOPE * v3;
        float e0 = __expf(fminf(v0, 60.f)), e1 = __expf(fminf(v1, 60.f));
        float e2 = __expf(fminf(v2, 60.f)), e3 = __expf(fminf(v3, 60.f));
        p[(size_t)j * NHEAD + h] = e0;
        p[(size_t)(j + 1) * NHEAD + h] = e1;
        p[(size_t)(j + 2) * NHEAD + h] = e2;
        p[(size_t)(j + 3) * NHEAD + h] = e3;
        sum += (e0 + e1) + (e2 + e3);
    }
    for (; j < e; j++) {
        float v = asrc[(size_t)ssrc[j] * NHEAD + h] + ad;
        v = (v > 0.f) ? v : NEG_SLOPE * v;
        float ex = __expf(fminf(v, 60.f));
        p[(size_t)j * NHEAD + h] = ex;
        sum += ex;
    }
    dinv[(size_t)n * NHEAD + h] = 1.0f / sum;
}

// ---------------- aggregation + BN + ReLU (softmax denom folded in) ----------
// 256-thread blocks (4 FULL live waves -> 8 blocks/CU = 32 gathering waves,
// vs 320-thread with a dead 5th wave). Covers feats 0..1023; the 16 tail
// feats (1024..1039, all head 7) are done by aggregate_tail.
__global__ __launch_bounds__(256, 8) void aggregate(
    const short* __restrict__ xh_bf, const float* __restrict__ p,
    const float* __restrict__ dinv,
    const int* __restrict__ off, const int* __restrict__ ssrc,
    const float* __restrict__ prev_f,     // fp32 residual (layer 1: x) or null
    const short* __restrict__ prev_bf,    // bf16 residual (layer 2: hA_bf) or null
    const float* __restrict__ b_att, const float* __restrict__ gamma,
    const float* __restrict__ beta, const float* __restrict__ mean,
    const float* __restrict__ var,
    short* __restrict__ hout_bf, int N) {
    int n = blockIdx.x;
    int t = threadIdx.x;
    int f0 = t * 4;                      // 0..1020
    int s = off[n], e = off[n + 1];
    const int hA = f0 / DHEAD;
    const int hB = (f0 + 3) / DHEAD;
    const int sp = hB * DHEAD - f0;      // feats i<sp use head hA (i in 0..3)
    float acc[4] = {0.f, 0.f, 0.f, 0.f};

    int j = s;
    for (; j + 8 <= e; j += 8) {
        int sj[8];
        ushort4 v[8];
#pragma unroll
        for (int u = 0; u < 8; u++) sj[u] = ssrc[j + u];
#pragma unroll
        for (int u = 0; u < 8; u++) v[u] = *(const ushort4*)(xh_bf + (size_t)sj[u] * FEAT + f0);
#pragma unroll
        for (int u = 0; u < 8; u++) {
            const float* pj = p + (size_t)(j + u) * NHEAD;
            float pa = pj[hA], pb = pj[hB];
            acc[0] += ((0 < sp) ? pa : pb) * bf2f((short)v[u].x);
            acc[1] += ((1 < sp) ? pa : pb) * bf2f((short)v[u].y);
            acc[2] += ((2 < sp) ? pa : pb) * bf2f((short)v[u].z);
            acc[3] += ((3 < sp) ? pa : pb) * bf2f((short)v[u].w);
        }
    }
    for (; j + 4 <= e; j += 4) {
        int sj[4];
        ushort4 v[4];
#pragma unroll
        for (int u = 0; u < 4; u++) sj[u] = ssrc[j + u];
#pragma unroll
        for (int u = 0; u < 4; u++) v[u] = *(const ushort4*)(xh_bf + (size_t)sj[u] * FEAT + f0);
#pragma unroll
        for (int u = 0; u < 4; u++) {
            const float* pj = p + (size_t)(j + u) * NHEAD;
            float pa = pj[hA], pb = pj[hB];
            acc[0] += ((0 < sp) ? pa : pb) * bf2f((short)v[u].x);
            acc[1] += ((1 < sp) ? pa : pb) * bf2f((short)v[u].y);
            acc[2] += ((2 < sp) ? pa : pb) * bf2f((short)v[u].z);
            acc[3] += ((3 < sp) ? pa : pb) * bf2f((short)v[u].w);
        }
    }
    for (; j < e; j++) {
        int src = ssrc[j];
        ushort4 v = *(const ushort4*)(xh_bf + (size_t)src * FEAT + f0);
        const float* pj = p + (size_t)j * NHEAD;
        float pa = pj[hA], pb = pj[hB];
        acc[0] += ((0 < sp) ? pa : pb) * bf2f((short)v.x);
        acc[1] += ((1 < sp) ? pa : pb) * bf2f((short)v.y);
        acc[2] += ((2 < sp) ? pa : pb) * bf2f((short)v.z);
        acc[3] += ((3 < sp) ? pa : pb) * bf2f((short)v.w);
    }

    float da = dinv[(size_t)n * NHEAD + hA];
    float db = dinv[(size_t)n * NHEAD + hB];
    acc[0] *= (0 < sp) ? da : db;
    acc[1] *= (1 < sp) ? da : db;
    acc[2] *= (2 < sp) ? da : db;
    acc[3] *= (3 < sp) ? da : db;

    float4 bv = *(const float4*)(b_att + f0);
    float4 gv = *(const float4*)(gamma + f0);
    float4 be = *(const float4*)(beta + f0);
    float4 mv = *(const float4*)(mean + f0);
    float4 vv = *(const float4*)(var + f0);
    float z[4] = {acc[0] + bv.x, acc[1] + bv.y, acc[2] + bv.z, acc[3] + bv.w};
    if (prev_f) {
        float4 pv = *(const float4*)(prev_f + (size_t)n * FEAT + f0);
        z[0] += pv.x; z[1] += pv.y; z[2] += pv.z; z[3] += pv.w;
    }
    if (prev_bf) {
        ushort4 pv = *(const ushort4*)(prev_bf + (size_t)n * KP + f0);
        z[0] += bf2f((short)pv.x); z[1] += bf2f((short)pv.y);
        z[2] += bf2f((short)pv.z); z[3] += bf2f((short)pv.w);
    }
    float g4[4] = {gv.x, gv.y, gv.z, gv.w};
    float b4[4] = {be.x, be.y, be.z, be.w};
    float m4[4] = {mv.x, mv.y, mv.z, mv.w};
    float v4[4] = {vv.x, vv.y, vv.z, vv.w};
    ushort4 o;
    unsigned short* op = (unsigned short*)&o;
#pragma unroll
    for (int i = 0; i < 4; i++) {
        float zz = (z[i] - m4[i]) * rsqrtf(v4[i] + BN_EPS) * g4[i] + b4[i];
        op[i] = (unsigned short)f2bf(fmaxf(zz, 0.f));
    }
    *(ushort4*)(hout_bf + (size_t)n * KP + f0) = o;
}

// tail feats 1024..1039 (head 7) for 64 nodes per block (4 threads/node)
__global__ void aggregate_tail(
    const short* __restrict__ xh_bf, const float* __restrict__ p,
    const float* __restrict__ dinv,
    const int* __restrict__ off, const int* __restrict__ ssrc,
    const float* __restrict__ prev_f, const short* __restrict__ prev_bf,
    const float* __restrict__ b_att, const float* __restrict__ gamma,
    const float* __restrict__ beta, const float* __restrict__ mean,
    const float* __restrict__ var,
    short* __restrict__ hout_bf, int N) {
    int t = threadIdx.x;
    int n = blockIdx.x * 64 + (t >> 2);
    if (n >= N) return;
    int f = 1024 + (t & 3) * 4;
    int s = off[n], e = off[n + 1];
    float acc[4] = {0.f, 0.f, 0.f, 0.f};
    int j = s;
    for (; j + 4 <= e; j += 4) {
        int s0 = ssrc[j], s1 = ssrc[j + 1], s2 = ssrc[j + 2], s3 = ssrc[j + 3];
        ushort4 v0 = *(const ushort4*)(xh_bf + (size_t)s0 * FEAT + f);
        ushort4 v1 = *(const ushort4*)(xh_bf + (size_t)s1 * FEAT + f);
        ushort4 v2 = *(const ushort4*)(xh_bf + (size_t)s2 * FEAT + f);
        ushort4 v3 = *(const ushort4*)(xh_bf + (size_t)s3 * FEAT + f);
        float p0 = p[(size_t)j * NHEAD + 7];
        float p1 = p[(size_t)(j + 1) * NHEAD + 7];
        float p2 = p[(size_t)(j + 2) * NHEAD + 7];
        float p3 = p[(size_t)(j + 3) * NHEAD + 7];
        acc[0] += p0 * bf2f((short)v0.x) + p1 * bf2f((short)v1.x)
                + p2 * bf2f((short)v2.x) + p3 * bf2f((short)v3.x);
        acc[1] += p0 * bf2f((short)v0.y) + p1 * bf2f((short)v1.y)
                + p2 * bf2f((short)v2.y) + p3 * bf2f((short)v3.y);
        acc[2] += p0 * bf2f((short)v0.z) + p1 * bf2f((short)v1.z)
                + p2 * bf2f((short)v2.z) + p3 * bf2f((short)v3.z);
        acc[3] += p0 * bf2f((short)v0.w) + p1 * bf2f((short)v1.w)
                + p2 * bf2f((short)v2.w) + p3 * bf2f((short)v3.w);
    }
    for (; j < e; j++) {
        int src = ssrc[j];
        ushort4 v = *(const ushort4*)(xh_bf + (size_t)src * FEAT + f);
        float pj = p[(size_t)j * NHEAD + 7];
        acc[0] += pj * bf2f((short)v.x);
        acc[1] += pj * bf2f((short)v.y);
        acc[2] += pj * bf2f((short)v.z);
        acc[3] += pj * bf2f((short)v.w);
    }
    float dv = dinv[(size_t)n * NHEAD + 7];
    acc[0] *= dv; acc[1] *= dv; acc[2] *= dv; acc[3] *= dv;

    float4 bv = *(const float4*)(b_att + f);
    float4 gv = *(const float4*)(gamma + f);
    float4 be = *(const float4*)(beta + f);
    float4 mv = *(const float4*)(mean + f);
    float4 vv = *(const float4*)(var + f);
    float z[4] = {acc[0] + bv.x, acc[1] + bv.y, acc[2] + bv.z, acc[3] + bv.w};
    if (prev_f) {
        float4 pv = *(const float4*)(prev_f + (size_t)n * FEAT + f);
        z[0] += pv.x; z[1] += pv.y; z[2] += pv.z; z[3] += pv.w;
    }
    if (prev_bf) {
        ushort4 pv = *(const ushort4*)(prev_bf + (size_t)n * KP + f);
        z[0] += bf2f((short)pv.x); z[1] += bf2f((short)pv.y);
        z[2] += bf2f((short)pv.z); z[3] += bf2f((short)pv.w);
    }
    float g4[4] = {gv.x, gv.y, gv.z, gv.w};
    float b4[4] = {be.x, be.y, be.z, be.w};
    float m4[4] = {mv.x, mv.y, mv.z, mv.w};
    float v4[4] = {vv.x, vv.y, vv.z, vv.w};
    ushort4 o;
    unsigned short* op = (unsigned short*)&o;
#pragma unroll
    for (int i = 0; i < 4; i++) {
        float zz = (z[i] - m4[i]) * rsqrtf(v4[i] + BN_EPS) * g4[i] + b4[i];
        op[i] = (unsigned short)f2bf(fmaxf(zz, 0.f));
    }
    *(ushort4*)(hout_bf + (size_t)n * KP + f) = o;
}

// ---------------- pooling over contiguous node ranges ----------------
__global__ __launch_bounds__(320) void pool_k(const short* __restrict__ h,
                                              const int* __restrict__ gstart,
                                              float* __restrict__ pooled) {
    int g = blockIdx.x;
    int t = threadIdx.x;
    if (t >= 260) return;
    int f0 = t * 4;
    int s = gstart[g], e = gstart[g + 1];
    float acc[4] = {0.f, 0.f, 0.f, 0.f};
    int n = s;
    for (; n + 4 <= e; n += 4) {
        ushort4 v0 = *(const ushort4*)(h + (size_t)n * KP + f0);
        ushort4 v1 = *(const ushort4*)(h + (size_t)(n + 1) * KP + f0);
        ushort4 v2 = *(const ushort4*)(h + (size_t)(n + 2) * KP + f0);
        ushort4 v3 = *(const ushort4*)(h + (size_t)(n + 3) * KP + f0);
        acc[0] += bf2f((short)v0.x) + bf2f((short)v1.x) + bf2f((short)v2.x) + bf2f((short)v3.x);
        acc[1] += bf2f((short)v0.y) + bf2f((short)v1.y) + bf2f((short)v2.y) + bf2f((short)v3.y);
        acc[2] += bf2f((short)v0.z) + bf2f((short)v1.z) + bf2f((short)v2.z) + bf2f((short)v3.z);
        acc[3] += bf2f((short)v0.w) + bf2f((short)v1.w) + bf2f((short)v2.w) + bf2f((short)v3.w);
    }
    for (; n < e; n++) {
        ushort4 v = *(const ushort4*)(h + (size_t)n * KP + f0);
        acc[0] += bf2f((short)v.x);
        acc[1] += bf2f((short)v.y);
        acc[2] += bf2f((short)v.z);
        acc[3] += bf2f((short)v.w);
    }
    *(float4*)(pooled + (size_t)g * FEAT + f0) = make_float4(acc[0], acc[1], acc[2], acc[3]);
}

__global__ void final_k(const float* __restrict__ pooled, const int* __restrict__ gstart,
                        const float* __restrict__ W_out, const float* __restrict__ b_out,
                        float* __restrict__ out) {
    int g = blockIdx.x >> 1, c = blockIdx.x & 1;
    int lane = threadIdx.x;  // 64
    float ssum = 0.f;
    for (int f = lane; f < FEAT; f += 64) ssum += pooled[(size_t)g * FEAT + f] * W_out[f * 2 + c];
#pragma unroll
    for (int o = 1; o < 64; o <<= 1) ssum += __shfl_xor(ssum, o);
    if (lane == 0) {
        float cnt = (float)(gstart[g + 1] - gstart[g]);
        float inv = 1.0f / fmaxf(cnt, 1.0f);
        out[g * 2 + c] = ssum * inv + b_out[c];
    }
}

// ---------------- launch ----------------
extern "C" void kernel_launch(void* const* d_in, const int* in_sizes, int n_in,
                              void* d_out, int out_size, void* d_ws, size_t ws_size,
                              hipStream_t stream) {
    const float* x       = (const float*)d_in[0];
    const int*   ei      = (const int*)d_in[1];
    const int*   batch   = (const int*)d_in[2];
    const float* W       = (const float*)d_in[3];
    const float* a_src   = (const float*)d_in[4];
    const float* a_dst   = (const float*)d_in[5];
    const float* b_att   = (const float*)d_in[6];
    const float* gamma   = (const float*)d_in[7];
    const float* beta    = (const float*)d_in[8];
    const float* r_mean  = (const float*)d_in[9];
    const float* r_var   = (const float*)d_in[10];
    const float* W_out   = (const float*)d_in[11];
    const float* b_out   = (const float*)d_in[12];
    float* out = (float*)d_out;

    const int N = in_sizes[0] / FEAT;
    const int E = in_sizes[1] / 2;
    const int E2 = E + N;
    const int MT = (N + 127) / 128;
    const int Mp = MT * 128;
    const int MTpad = ((MT + 7) / 8) * 8;
    const int NB = (N + 1023) / 1024;

    char* w = (char*)d_ws;
    auto alloc = [&](size_t bytes) {
        void* pp = (void*)w;
        w += (bytes + 255) & ~(size_t)255;
        return pp;
    };
    short* xh_bf  = (short*)alloc((size_t)N * FEAT * 2);
    short* x_bf   = (short*)alloc((size_t)Mp * KP * 2);   // layer-0 A; reused as layer-3 h
    short* hA_bf  = (short*)alloc((size_t)Mp * KP * 2);
    short* hB_bf  = (short*)alloc((size_t)Mp * KP * 2);
    short* Bt3    = (short*)alloc((size_t)NLAYER * NP * KP * 2);
    float* p      = (float*)alloc((size_t)E2 * NHEAD * 4);
    float* asrc   = (float*)alloc((size_t)N * NHEAD * 4);
    float* adst   = (float*)alloc((size_t)N * NHEAD * 4);
    float* dinv   = (float*)alloc((size_t)N * NHEAD * 4);
    int*   src2   = (int*)alloc((size_t)E2 * 4);
    int*   dst2   = (int*)alloc((size_t)E2 * 4);
    int*   ssrc   = (int*)alloc((size_t)E2 * 4);
    int*   deg    = (int*)alloc((size_t)N * 4);
    int*   off    = (int*)alloc((size_t)(N + 1) * 4);
    int*   cursor = (int*)alloc((size_t)N * 4);
    int*   part   = (int*)alloc((size_t)(NB + 1) * 4);
    int*   gstart = (int*)alloc((size_t)(NGRAPH + 1) * 4);
    float* pooled = (float*)alloc((size_t)NGRAPH * FEAT * 4);

    hipMemsetAsync(deg, 0, (size_t)N * 4, stream);
    hipMemsetAsync(Bt3, 0, (size_t)NLAYER * NP * KP * 2, stream);

    conv_pad_x<<<(Mp * (KP / 8) + 255) / 256, 256, 0, stream>>>(x, x_bf, N, Mp);
    pad_bf<<<Mp, 64, 0, stream>>>(hA_bf, N);
    pad_bf<<<Mp, 64, 0, stream>>>(hB_bf, N);
    dim3 tgrid((FEAT + 31) / 32, (FEAT + 31) / 32, NLAYER);
    transpose_w<<<tgrid, 256, 0, stream>>>(W, Bt3);
    wa_kernel<<<(NLAYER * FEAT * NHEAD + 255) / 256, 256, 0, stream>>>(W, a_src, a_dst, Bt3);

    build_edges<<<(E2 + 255) / 256, 256, 0, stream>>>(ei, E, N, src2, dst2, deg);
    scan_part<<<NB, 1024, 0, stream>>>(deg, off, part, N);
    scan_carry<<<1, 64, 0, stream>>>(part, off, NB, N);
    scan_add<<<(N + 255) / 256, 256, 0, stream>>>(part, off, cursor, N);
    scatter_k<<<(E2 + 255) / 256, 256, 0, stream>>>(src2, dst2, cursor, ssrc, E2);
    gstart_k<<<(N + 255) / 256, 256, 0, stream>>>(batch, gstart, N);

    const short* hin[NLAYER]     = {x_bf, hA_bf, hB_bf};
    const float* prevf[NLAYER]   = {nullptr, x, nullptr};
    const short* prevbf[NLAYER]  = {nullptr, nullptr, hA_bf};
    short* houtl[NLAYER]         = {hA_bf, hB_bf, x_bf};

    for (int l = 0; l < NLAYER; l++) {
        gemm_mfma<<<MTpad * 9, 256, 0, stream>>>(hin[l], Bt3 + (size_t)l * NP * KP,
                                                 xh_bf, asrc, adst, N, MT);
        att_softmax<<<(N * NHEAD + 255) / 256, 256, 0, stream>>>(off, ssrc, asrc, adst, p, dinv, N);
        aggregate<<<N, 256, 0, stream>>>(xh_bf, p, dinv, off, ssrc, prevf[l], prevbf[l],
                                         b_att + l * FEAT, gamma + l * FEAT, beta + l * FEAT,
                                         r_mean + l * FEAT, r_var + l * FEAT,
                                         houtl[l], N);
        aggregate_tail<<<(N + 63) / 64, 256, 0, stream>>>(xh_bf, p, dinv, off, ssrc,
                                         prevf[l], prevbf[l],
                                         b_att + l * FEAT, gamma + l * FEAT, beta + l * FEAT,
                                         r_mean + l * FEAT, r_var + l * FEAT,
                                         houtl[l], N);
    }

    pool_k<<<NGRAPH, 320, 0, stream>>>(x_bf, gstart, pooled);
    final_k<<<NGRAPH * 2, 64, 0, stream>>>(pooled, gstart, W_out, b_out, out);
}

// Round 8
// 1021.702 us; speedup vs baseline: 1.3600x; 1.0336x over previous
//
#include <hip/hip_runtime.h>
#include <hip/hip_bf16.h>
#include <math.h>

#define FEAT 1040
#define NHEAD 8
#define DHEAD 130
#define NLAYER 3
#define NGRAPH 64
#define NEG_SLOPE 0.2f
#define BN_EPS 1e-5f
#define KP 1056   // FEAT padded to multiple of 32 (K of GEMM)
#define NP 1152   // FEAT padded to multiple of 128; cols 1040..1055 = wa_src/wa_dst
#define NKT (KP / 32)   // 33 K-tiles

typedef float floatx4 __attribute__((ext_vector_type(4)));
typedef short shortx8 __attribute__((ext_vector_type(8)));

__device__ __forceinline__ short f2bf(float f) {
    unsigned u = __float_as_uint(f);
    u += 0x7fff + ((u >> 16) & 1);   // round-to-nearest-even
    return (short)(u >> 16);
}
__device__ __forceinline__ float bf2f(short b) {
    return __uint_as_float(((unsigned)(unsigned short)b) << 16);
}
__device__ __forceinline__ float att_p(float a, float ad) {
    float v = a + ad;
    v = (v > 0.f) ? v : NEG_SLOPE * v;
    return __expf(fminf(v, 60.f));   // one-pass softmax numerator (R4-verified)
}

__device__ __forceinline__ void async16(const void* g, void* l) {
    __builtin_amdgcn_global_load_lds(
        (const __attribute__((address_space(1))) unsigned int*)g,
        (__attribute__((address_space(3))) unsigned int*)l, 16, 0, 0);
}

// ---------------- bf16 MFMA GEMM ----------------
// 3-buffer LDS ring, prefetch distance 2, counted s_waitcnt vmcnt(4).
// Coalesced epilogue via LDS C-stage (stride 136).
__global__ __launch_bounds__(256) void gemm_mfma(const short* __restrict__ A,
                                                 const short* __restrict__ Bt,
                                                 short* __restrict__ xh_bf,
                                                 float* __restrict__ asrc,
                                                 float* __restrict__ adst,
                                                 int M, int MT) {
    const int lid = blockIdx.x;
    const int g = lid / 72, r = lid % 72;
    const int bmi = g * 8 + (r & 7);
    const int bni = r >> 3;
    if (bmi >= MT) return;
    const int bm = bmi * 128;
    const int bn = bni * 128;

    __shared__ short lds[24576];   // 48 KB: As[3][4096] | Bs[3][4096]; epilogue reuses as C
    short (*As)[4096] = (short (*)[4096])lds;
    short (*Bs)[4096] = (short (*)[4096])&lds[12288];
    short* Cs = lds;               // 128*136 shorts for epilogue

    const int tid = threadIdx.x;
    const int lane = tid & 63;
    const int w = tid >> 6;
    const int wm = (w & 1) * 64;
    const int wn = (w >> 1) * 64;

    const int tt0 = tid, tt1 = 256 + tid;
    const int row0 = ((tt0 >> 6) << 4) | (tt0 & 15);
    const int col0 = ((tt0 >> 4) & 3) * 8;
    const int row1 = ((tt1 >> 6) << 4) | (tt1 & 15);
    const int col1 = ((tt1 >> 4) & 3) * 8;

    const short* gA0 = A + (size_t)(bm + row0) * KP + col0;
    const short* gA1 = A + (size_t)(bm + row1) * KP + col1;
    const short* gB0 = Bt + (size_t)(bn + row0) * KP + col0;
    const short* gB1 = Bt + (size_t)(bn + row1) * KP + col1;

    const int fr = lane & 15;
    const int kq = lane >> 4;

    floatx4 acc[4][4];
#pragma unroll
    for (int i = 0; i < 4; i++)
#pragma unroll
        for (int j = 0; j < 4; j++) acc[i][j] = (floatx4){0.f, 0.f, 0.f, 0.f};

    async16(gA0, &As[0][tt0 * 8]);
    async16(gA1, &As[0][tt1 * 8]);
    async16(gB0, &Bs[0][tt0 * 8]);
    async16(gB1, &Bs[0][tt1 * 8]);
    async16(gA0 + 32, &As[1][tt0 * 8]);
    async16(gA1 + 32, &As[1][tt1 * 8]);
    async16(gB0 + 32, &Bs[1][tt0 * 8]);
    async16(gB1 + 32, &Bs[1][tt1 * 8]);

    int cur = 0;
    for (int it = 0; it < NKT; ++it) {
        if (it == NKT - 1) {
            asm volatile("s_waitcnt vmcnt(0)" ::: "memory");
        } else {
            asm volatile("s_waitcnt vmcnt(4)" ::: "memory");
        }
        __builtin_amdgcn_s_barrier();
        __builtin_amdgcn_sched_barrier(0);
        if (it + 2 < NKT) {
            int pf = cur + 2; if (pf >= 3) pf -= 3;
            const int kp = (it + 2) * 32;
            async16(gA0 + kp, &As[pf][tt0 * 8]);
            async16(gA1 + kp, &As[pf][tt1 * 8]);
            async16(gB0 + kp, &Bs[pf][tt0 * 8]);
            async16(gB1 + kp, &Bs[pf][tt1 * 8]);
        }
        shortx8 af[4], bfr[4];
#pragma unroll
        for (int i = 0; i < 4; i++) {
            af[i]  = *(const shortx8*)&As[cur][((wm >> 4) + i) * 512 + kq * 128 + fr * 8];
            bfr[i] = *(const shortx8*)&Bs[cur][((wn >> 4) + i) * 512 + kq * 128 + fr * 8];
        }
#pragma unroll
        for (int i = 0; i < 4; i++)
#pragma unroll
            for (int j = 0; j < 4; j++)
                acc[i][j] = __builtin_amdgcn_mfma_f32_16x16x32_bf16(af[i], bfr[j], acc[i][j], 0, 0, 0);
        cur = (cur == 2) ? 0 : cur + 1;
    }

    const int rbase = (lane >> 4) * 4;
    const int ccol = lane & 15;

    if (bni < 8) {
        __syncthreads();
#pragma unroll
        for (int j = 0; j < 4; j++)
#pragma unroll
            for (int i = 0; i < 4; i++) {
                int rl = wm + i * 16 + rbase;
                int cl = wn + j * 16 + ccol;
#pragma unroll
                for (int r2 = 0; r2 < 4; r2++)
                    Cs[(rl + r2) * 136 + cl] = f2bf(acc[i][j][r2]);
            }
        __syncthreads();
        const int srow = tid >> 1, shalf = tid & 1;
        const int grow = bm + srow;
        if (grow < M) {
            const short* src = &Cs[srow * 136 + shalf * 64];
            short* dst = xh_bf + (size_t)grow * FEAT + bn + shalf * 64;
#pragma unroll
            for (int c8 = 0; c8 < 8; c8++)
                *(shortx8*)(dst + c8 * 8) = *(const shortx8*)(src + c8 * 8);
        }
    } else {
#pragma unroll
        for (int j = 0; j < 4; j++) {
            int colbase = bn + wn + j * 16;
            if (colbase < FEAT) {
                int col = colbase + ccol;
#pragma unroll
                for (int i = 0; i < 4; i++)
#pragma unroll
                    for (int r2 = 0; r2 < 4; r2++) {
                        int row = bm + wm + i * 16 + rbase + r2;
                        if (row < M) xh_bf[(size_t)row * FEAT + col] = f2bf(acc[i][j][r2]);
                    }
            } else if (colbase == FEAT) {
                int c = ccol;
                float* tgt = (c < 8) ? asrc : adst;
                int h = c & 7;
#pragma unroll
                for (int i = 0; i < 4; i++)
#pragma unroll
                    for (int r2 = 0; r2 < 4; r2++) {
                        int row = bm + wm + i * 16 + rbase + r2;
                        if (row < M) tgt[(size_t)row * NHEAD + h] = acc[i][j][r2];
                    }
            }
        }
    }
}

// ---------------- conversions / padding ----------------
__global__ void conv_pad_x(const float* __restrict__ x, short* __restrict__ out,
                           int N, int Mp) {
    int idx = blockIdx.x * 256 + threadIdx.x;   // index of 8-elem group
    int total = Mp * (KP / 8);
    if (idx >= total) return;
    int r = idx / (KP / 8), c = (idx - r * (KP / 8)) * 8;
    shortx8 o = (shortx8){0, 0, 0, 0, 0, 0, 0, 0};
    if (r < N && c < FEAT) {
        float4 v0 = *(const float4*)(x + (size_t)r * FEAT + c);
        float4 v1 = *(const float4*)(x + (size_t)r * FEAT + c + 4);
        o[0] = f2bf(v0.x); o[1] = f2bf(v0.y); o[2] = f2bf(v0.z); o[3] = f2bf(v0.w);
        o[4] = f2bf(v1.x); o[5] = f2bf(v1.y); o[6] = f2bf(v1.z); o[7] = f2bf(v1.w);
    }
    *(shortx8*)(out + (size_t)r * KP + c) = o;
}

__global__ void pad_bf(short* __restrict__ buf, int Mvalid) {
    int r = blockIdx.x;
    short* row = buf + (size_t)r * KP;
    if (r < Mvalid) {
        if (threadIdx.x < KP - FEAT) row[FEAT + threadIdx.x] = 0;
    } else {
        for (int c = threadIdx.x; c < KP; c += 64) row[c] = 0;
    }
}

__global__ void transpose_w(const float* __restrict__ W, short* __restrict__ Bt3) {
    __shared__ float t[32][33];
    int l = blockIdx.z;
    const float* Wl = W + (size_t)l * FEAT * FEAT;
    short* Bt = Bt3 + (size_t)l * NP * KP;
    int kb = blockIdx.x * 32, nb = blockIdx.y * 32;
    int tx = threadIdx.x & 31, ty = threadIdx.x >> 5;
#pragma unroll
    for (int i = 0; i < 4; i++) {
        int k = kb + ty + i * 8, n = nb + tx;
        t[ty + i * 8][tx] = (k < FEAT && n < FEAT) ? Wl[(size_t)k * FEAT + n] : 0.f;
    }
    __syncthreads();
#pragma unroll
    for (int i = 0; i < 4; i++) {
        int n = nb + ty + i * 8, k = kb + tx;
        if (n < FEAT && k < FEAT) Bt[(size_t)n * KP + k] = f2bf(t[tx][ty + i * 8]);
    }
}

__global__ void wa_kernel(const float* __restrict__ W, const float* __restrict__ a_s,
                          const float* __restrict__ a_d, short* __restrict__ Bt3) {
    int t = blockIdx.x * 256 + threadIdx.x;
    if (t >= NLAYER * FEAT * NHEAD) return;
    int h = t & 7;
    int f = (t >> 3) % FEAT;
    int l = t / (FEAT * NHEAD);
    const float* wrow = W + (((size_t)l * FEAT + f) * NHEAD + h) * DHEAD;
    const float* as = a_s + ((size_t)l * NHEAD + h) * DHEAD;
    const float* ad = a_d + ((size_t)l * NHEAD + h) * DHEAD;
    float ws = 0.f, wd = 0.f;
    for (int d = 0; d < DHEAD; d++) {
        float wv = wrow[d];
        ws += wv * as[d];
        wd += wv * ad[d];
    }
    short* base = Bt3 + (size_t)l * NP * KP;
    base[(size_t)(FEAT + h) * KP + f] = f2bf(ws);
    base[(size_t)(FEAT + 8 + h) * KP + f] = f2bf(wd);
}

// ---------------- graph preprocessing ----------------
__global__ void build_edges(const int* __restrict__ ei, int E, int N,
                            int* __restrict__ src2, int* __restrict__ dst2,
                            int* __restrict__ deg) {
    int e = blockIdx.x * 256 + threadIdx.x;
    int E2 = E + N;
    if (e >= E2) return;
    int s, d;
    if (e < E) { s = ei[e]; d = ei[E + e]; }
    else       { s = e - E; d = e - E; }
    src2[e] = s;
    dst2[e] = d;
    atomicAdd(&deg[d], 1);
}

__global__ void scan_part(const int* __restrict__ deg, int* __restrict__ off,
                          int* __restrict__ part, int N) {
    __shared__ int wsum[16];
    int tid = threadIdx.x;
    int i = blockIdx.x * 1024 + tid;
    int lane = tid & 63, wid = tid >> 6;
    int v = (i < N) ? deg[i] : 0;
    int incl = v;
#pragma unroll
    for (int o = 1; o < 64; o <<= 1) {
        int u = __shfl_up(incl, o);
        if (lane >= o) incl += u;
    }
    if (lane == 63) wsum[wid] = incl;
    __syncthreads();
    if (wid == 0) {
        int wv = (lane < 16) ? wsum[lane] : 0;
        int wincl = wv;
#pragma unroll
        for (int o = 1; o < 16; o <<= 1) {
            int u = __shfl_up(wincl, o);
            if (lane >= o) wincl += u;
        }
        if (lane < 16) wsum[lane] = wincl - wv;
    }
    __syncthreads();
    int excl = wsum[wid] + incl - v;
    if (i < N) off[i] = excl;
    if (tid == 1023) part[blockIdx.x] = wsum[15] + incl;
}

__global__ void scan_carry(int* __restrict__ part, int* __restrict__ off,
                           int NB, int N) {
    int lane = threadIdx.x;   // 64
    int run = 0;
    for (int base = 0; base < NB; base += 64) {
        int idx = base + lane;
        int v = (idx < NB) ? part[idx] : 0;
        int incl = v;
#pragma unroll
        for (int o = 1; o < 64; o <<= 1) {
            int u = __shfl_up(incl, o);
            if (lane >= o) incl += u;
        }
        if (idx < NB) part[idx] = run + incl - v;
        run += __shfl(incl, 63);
    }
    if (lane == 0) off[N] = run;
}

__global__ void scan_add(const int* __restrict__ part, int* __restrict__ off,
                         int* __restrict__ cursor, int N) {
    int i = blockIdx.x * 256 + threadIdx.x;
    if (i >= N) return;
    int o = off[i] + part[i >> 10];
    off[i] = o;
    cursor[i] = o;
}

__global__ void scatter_k(const int* __restrict__ src2, const int* __restrict__ dst2,
                          int* __restrict__ cursor, int* __restrict__ ssrc, int E2) {
    int e = blockIdx.x * 256 + threadIdx.x;
    if (e >= E2) return;
    int d = dst2[e];
    int pos = atomicAdd(&cursor[d], 1);
    ssrc[pos] = src2[e];
}

__global__ void gstart_k(const int* __restrict__ batch, int* __restrict__ gstart, int N) {
    int n = blockIdx.x * 256 + threadIdx.x;
    if (n >= N) return;
    int b = batch[n];
    if (n == 0) {
        for (int g = 0; g <= b; g++) gstart[g] = 0;
    } else {
        int pb = batch[n - 1];
        for (int g = pb + 1; g <= b; g++) gstart[g] = n;
    }
    if (n == N - 1) {
        for (int g = b + 1; g <= NGRAPH; g++) gstart[g] = N;
    }
}

// ---------------- fused softmax + aggregation + BN + ReLU ----------------
// R7 structure (256 thr = 4 full waves, 1 node/block, 8-B gathers) but the
// per-edge p[] loads are replaced by computing exp(leaky(asrc+adst)) inline
// (same VMEM count: 2x 4B loads from L2-resident asrc instead of p) and the
// softmax denominator is accumulated in-thread over the same loop. Kills the
// att_softmax kernel and the p/dinv buffers entirely.
__global__ __launch_bounds__(256, 8) void aggregate(
    const short* __restrict__ xh_bf,
    const float* __restrict__ asrc, const float* __restrict__ adst,
    const int* __restrict__ off, const int* __restrict__ ssrc,
    const float* __restrict__ prev_f,     // fp32 residual (layer 1: x) or null
    const short* __restrict__ prev_bf,    // bf16 residual (layer 2: hA_bf) or null
    const float* __restrict__ b_att, const float* __restrict__ gamma,
    const float* __restrict__ beta, const float* __restrict__ mean,
    const float* __restrict__ var,
    short* __restrict__ hout_bf, int N) {
    int n = blockIdx.x;
    int t = threadIdx.x;
    int f0 = t * 4;                      // 0..1020
    int s = off[n], e = off[n + 1];
    const int hA = f0 / DHEAD;
    const int hB = (f0 + 3) / DHEAD;
    const int sp = hB * DHEAD - f0;      // feats i<sp use head hA (i in 0..3)
    const float adA = adst[(size_t)n * NHEAD + hA];
    const float adB = adst[(size_t)n * NHEAD + hB];
    float acc[4] = {0.f, 0.f, 0.f, 0.f};
    float psA = 0.f, psB = 0.f;

    int j = s;
    for (; j + 8 <= e; j += 8) {
        int sj[8];
        ushort4 v[8];
#pragma unroll
        for (int u = 0; u < 8; u++) sj[u] = ssrc[j + u];
#pragma unroll
        for (int u = 0; u < 8; u++) v[u] = *(const ushort4*)(xh_bf + (size_t)sj[u] * FEAT + f0);
#pragma unroll
        for (int u = 0; u < 8; u++) {
            const float* ar = asrc + (size_t)sj[u] * NHEAD;
            float pa = att_p(ar[hA], adA);
            float pb = att_p(ar[hB], adB);
            psA += pa; psB += pb;
            acc[0] += ((0 < sp) ? pa : pb) * bf2f((short)v[u].x);
            acc[1] += ((1 < sp) ? pa : pb) * bf2f((short)v[u].y);
            acc[2] += ((2 < sp) ? pa : pb) * bf2f((short)v[u].z);
            acc[3] += ((3 < sp) ? pa : pb) * bf2f((short)v[u].w);
        }
    }
    for (; j + 4 <= e; j += 4) {
        int sj[4];
        ushort4 v[4];
#pragma unroll
        for (int u = 0; u < 4; u++) sj[u] = ssrc[j + u];
#pragma unroll
        for (int u = 0; u < 4; u++) v[u] = *(const ushort4*)(xh_bf + (size_t)sj[u] * FEAT + f0);
#pragma unroll
        for (int u = 0; u < 4; u++) {
            const float* ar = asrc + (size_t)sj[u] * NHEAD;
            float pa = att_p(ar[hA], adA);
            float pb = att_p(ar[hB], adB);
            psA += pa; psB += pb;
            acc[0] += ((0 < sp) ? pa : pb) * bf2f((short)v[u].x);
            acc[1] += ((1 < sp) ? pa : pb) * bf2f((short)v[u].y);
            acc[2] += ((2 < sp) ? pa : pb) * bf2f((short)v[u].z);
            acc[3] += ((3 < sp) ? pa : pb) * bf2f((short)v[u].w);
        }
    }
    for (; j < e; j++) {
        int src = ssrc[j];
        ushort4 v = *(const ushort4*)(xh_bf + (size_t)src * FEAT + f0);
        const float* ar = asrc + (size_t)src * NHEAD;
        float pa = att_p(ar[hA], adA);
        float pb = att_p(ar[hB], adB);
        psA += pa; psB += pb;
        acc[0] += ((0 < sp) ? pa : pb) * bf2f((short)v.x);
        acc[1] += ((1 < sp) ? pa : pb) * bf2f((short)v.y);
        acc[2] += ((2 < sp) ? pa : pb) * bf2f((short)v.z);
        acc[3] += ((3 < sp) ? pa : pb) * bf2f((short)v.w);
    }

    float da = 1.0f / psA;
    float db = 1.0f / psB;
    acc[0] *= (0 < sp) ? da : db;
    acc[1] *= (1 < sp) ? da : db;
    acc[2] *= (2 < sp) ? da : db;
    acc[3] *= (3 < sp) ? da : db;

    float4 bv = *(const float4*)(b_att + f0);
    float4 gv = *(const float4*)(gamma + f0);
    float4 be = *(const float4*)(beta + f0);
    float4 mv = *(const float4*)(mean + f0);
    float4 vv = *(const float4*)(var + f0);
    float z[4] = {acc[0] + bv.x, acc[1] + bv.y, acc[2] + bv.z, acc[3] + bv.w};
    if (prev_f) {
        float4 pv = *(const float4*)(prev_f + (size_t)n * FEAT + f0);
        z[0] += pv.x; z[1] += pv.y; z[2] += pv.z; z[3] += pv.w;
    }
    if (prev_bf) {
        ushort4 pv = *(const ushort4*)(prev_bf + (size_t)n * KP + f0);
        z[0] += bf2f((short)pv.x); z[1] += bf2f((short)pv.y);
        z[2] += bf2f((short)pv.z); z[3] += bf2f((short)pv.w);
    }
    float g4[4] = {gv.x, gv.y, gv.z, gv.w};
    float b4[4] = {be.x, be.y, be.z, be.w};
    float m4[4] = {mv.x, mv.y, mv.z, mv.w};
    float v4[4] = {vv.x, vv.y, vv.z, vv.w};
    ushort4 o;
    unsigned short* op = (unsigned short*)&o;
#pragma unroll
    for (int i = 0; i < 4; i++) {
        float zz = (z[i] - m4[i]) * rsqrtf(v4[i] + BN_EPS) * g4[i] + b4[i];
        op[i] = (unsigned short)f2bf(fmaxf(zz, 0.f));
    }
    *(ushort4*)(hout_bf + (size_t)n * KP + f0) = o;
}

// tail feats 1024..1039 (head 7) for 64 nodes per block (4 threads/node)
__global__ void aggregate_tail(
    const short* __restrict__ xh_bf,
    const float* __restrict__ asrc, const float* __restrict__ adst,
    const int* __restrict__ off, const int* __restrict__ ssrc,
    const float* __restrict__ prev_f, const short* __restrict__ prev_bf,
    const float* __restrict__ b_att, const float* __restrict__ gamma,
    const float* __restrict__ beta, const float* __restrict__ mean,
    const float* __restrict__ var,
    short* __restrict__ hout_bf, int N) {
    int t = threadIdx.x;
    int n = blockIdx.x * 64 + (t >> 2);
    if (n >= N) return;
    int f = 1024 + (t & 3) * 4;
    int s = off[n], e = off[n + 1];
    const float ad7 = adst[(size_t)n * NHEAD + 7];
    float acc[4] = {0.f, 0.f, 0.f, 0.f};
    float ps = 0.f;
    for (int j = s; j < e; j++) {
        int src = ssrc[j];
        ushort4 v = *(const ushort4*)(xh_bf + (size_t)src * FEAT + f);
        float pj = att_p(asrc[(size_t)src * NHEAD + 7], ad7);
        ps += pj;
        acc[0] += pj * bf2f((short)v.x);
        acc[1] += pj * bf2f((short)v.y);
        acc[2] += pj * bf2f((short)v.z);
        acc[3] += pj * bf2f((short)v.w);
    }
    float dv = 1.0f / ps;
    acc[0] *= dv; acc[1] *= dv; acc[2] *= dv; acc[3] *= dv;

    float4 bv = *(const float4*)(b_att + f);
    float4 gv = *(const float4*)(gamma + f);
    float4 be = *(const float4*)(beta + f);
    float4 mv = *(const float4*)(mean + f);
    float4 vv = *(const float4*)(var + f);
    float z[4] = {acc[0] + bv.x, acc[1] + bv.y, acc[2] + bv.z, acc[3] + bv.w};
    if (prev_f) {
        float4 pv = *(const float4*)(prev_f + (size_t)n * FEAT + f);
        z[0] += pv.x; z[1] += pv.y; z[2] += pv.z; z[3] += pv.w;
    }
    if (prev_bf) {
        ushort4 pv = *(const ushort4*)(prev_bf + (size_t)n * KP + f);
        z[0] += bf2f((short)pv.x); z[1] += bf2f((short)pv.y);
        z[2] += bf2f((short)pv.z); z[3] += bf2f((short)pv.w);
    }
    float g4[4] = {gv.x, gv.y, gv.z, gv.w};
    float b4[4] = {be.x, be.y, be.z, be.w};
    float m4[4] = {mv.x, mv.y, mv.z, mv.w};
    float v4[4] = {vv.x, vv.y, vv.z, vv.w};
    ushort4 o;
    unsigned short* op = (unsigned short*)&o;
#pragma unroll
    for (int i = 0; i < 4; i++) {
        float zz = (z[i] - m4[i]) * rsqrtf(v4[i] + BN_EPS) * g4[i] + b4[i];
        op[i] = (unsigned short)f2bf(fmaxf(zz, 0.f));
    }
    *(ushort4*)(hout_bf + (size_t)n * KP + f) = o;
}

// ---------------- pooling over contiguous node ranges ----------------
__global__ __launch_bounds__(320) void pool_k(const short* __restrict__ h,
                                              const int* __restrict__ gstart,
                                              float* __restrict__ pooled) {
    int g = blockIdx.x;
    int t = threadIdx.x;
    if (t >= 260) return;
    int f0 = t * 4;
    int s = gstart[g], e = gstart[g + 1];
    float acc[4] = {0.f, 0.f, 0.f, 0.f};
    int n = s;
    for (; n + 4 <= e; n += 4) {
        ushort4 v0 = *(const ushort4*)(h + (size_t)n * KP + f0);
        ushort4 v1 = *(const ushort4*)(h + (size_t)(n + 1) * KP + f0);
        ushort4 v2 = *(const ushort4*)(h + (size_t)(n + 2) * KP + f0);
        ushort4 v3 = *(const ushort4*)(h + (size_t)(n + 3) * KP + f0);
        acc[0] += bf2f((short)v0.x) + bf2f((short)v1.x) + bf2f((short)v2.x) + bf2f((short)v3.x);
        acc[1] += bf2f((short)v0.y) + bf2f((short)v1.y) + bf2f((short)v2.y) + bf2f((short)v3.y);
        acc[2] += bf2f((short)v0.z) + bf2f((short)v1.z) + bf2f((short)v2.z) + bf2f((short)v3.z);
        acc[3] += bf2f((short)v0.w) + bf2f((short)v1.w) + bf2f((short)v2.w) + bf2f((short)v3.w);
    }
    for (; n < e; n++) {
        ushort4 v = *(const ushort4*)(h + (size_t)n * KP + f0);
        acc[0] += bf2f((short)v.x);
        acc[1] += bf2f((short)v.y);
        acc[2] += bf2f((short)v.z);
        acc[3] += bf2f((short)v.w);
    }
    *(float4*)(pooled + (size_t)g * FEAT + f0) = make_float4(acc[0], acc[1], acc[2], acc[3]);
}

__global__ void final_k(const float* __restrict__ pooled, const int* __restrict__ gstart,
                        const float* __restrict__ W_out, const float* __restrict__ b_out,
                        float* __restrict__ out) {
    int g = blockIdx.x >> 1, c = blockIdx.x & 1;
    int lane = threadIdx.x;  // 64
    float ssum = 0.f;
    for (int f = lane; f < FEAT; f += 64) ssum += pooled[(size_t)g * FEAT + f] * W_out[f * 2 + c];
#pragma unroll
    for (int o = 1; o < 64; o <<= 1) ssum += __shfl_xor(ssum, o);
    if (lane == 0) {
        float cnt = (float)(gstart[g + 1] - gstart[g]);
        float inv = 1.0f / fmaxf(cnt, 1.0f);
        out[g * 2 + c] = ssum * inv + b_out[c];
    }
}

// ---------------- launch ----------------
extern "C" void kernel_launch(void* const* d_in, const int* in_sizes, int n_in,
                              void* d_out, int out_size, void* d_ws, size_t ws_size,
                              hipStream_t stream) {
    const float* x       = (const float*)d_in[0];
    const int*   ei      = (const int*)d_in[1];
    const int*   batch   = (const int*)d_in[2];
    const float* W       = (const float*)d_in[3];
    const float* a_src   = (const float*)d_in[4];
    const float* a_dst   = (const float*)d_in[5];
    const float* b_att   = (const float*)d_in[6];
    const float* gamma   = (const float*)d_in[7];
    const float* beta    = (const float*)d_in[8];
    const float* r_mean  = (const float*)d_in[9];
    const float* r_var   = (const float*)d_in[10];
    const float* W_out   = (const float*)d_in[11];
    const float* b_out   = (const float*)d_in[12];
    float* out = (float*)d_out;

    const int N = in_sizes[0] / FEAT;
    const int E = in_sizes[1] / 2;
    const int E2 = E + N;
    const int MT = (N + 127) / 128;
    const int Mp = MT * 128;
    const int MTpad = ((MT + 7) / 8) * 8;
    const int NB = (N + 1023) / 1024;

    char* w = (char*)d_ws;
    auto alloc = [&](size_t bytes) {
        void* pp = (void*)w;
        w += (bytes + 255) & ~(size_t)255;
        return pp;
    };
    short* xh_bf  = (short*)alloc((size_t)N * FEAT * 2);
    short* x_bf   = (short*)alloc((size_t)Mp * KP * 2);   // layer-0 A; reused as layer-3 h
    short* hA_bf  = (short*)alloc((size_t)Mp * KP * 2);
    short* hB_bf  = (short*)alloc((size_t)Mp * KP * 2);
    short* Bt3    = (short*)alloc((size_t)NLAYER * NP * KP * 2);
    float* asrc   = (float*)alloc((size_t)N * NHEAD * 4);
    float* adst   = (float*)alloc((size_t)N * NHEAD * 4);
    int*   src2   = (int*)alloc((size_t)E2 * 4);
    int*   dst2   = (int*)alloc((size_t)E2 * 4);
    int*   ssrc   = (int*)alloc((size_t)E2 * 4);
    int*   deg    = (int*)alloc((size_t)N * 4);
    int*   off    = (int*)alloc((size_t)(N + 1) * 4);
    int*   cursor = (int*)alloc((size_t)N * 4);
    int*   part   = (int*)alloc((size_t)(NB + 1) * 4);
    int*   gstart = (int*)alloc((size_t)(NGRAPH + 1) * 4);
    float* pooled = (float*)alloc((size_t)NGRAPH * FEAT * 4);

    hipMemsetAsync(deg, 0, (size_t)N * 4, stream);
    hipMemsetAsync(Bt3, 0, (size_t)NLAYER * NP * KP * 2, stream);

    conv_pad_x<<<(Mp * (KP / 8) + 255) / 256, 256, 0, stream>>>(x, x_bf, N, Mp);
    pad_bf<<<Mp, 64, 0, stream>>>(hA_bf, N);
    pad_bf<<<Mp, 64, 0, stream>>>(hB_bf, N);
    dim3 tgrid((FEAT + 31) / 32, (FEAT + 31) / 32, NLAYER);
    transpose_w<<<tgrid, 256, 0, stream>>>(W, Bt3);
    wa_kernel<<<(NLAYER * FEAT * NHEAD + 255) / 256, 256, 0, stream>>>(W, a_src, a_dst, Bt3);

    build_edges<<<(E2 + 255) / 256, 256, 0, stream>>>(ei, E, N, src2, dst2, deg);
    scan_part<<<NB, 1024, 0, stream>>>(deg, off, part, N);
    scan_carry<<<1, 64, 0, stream>>>(part, off, NB, N);
    scan_add<<<(N + 255) / 256, 256, 0, stream>>>(part, off, cursor, N);
    scatter_k<<<(E2 + 255) / 256, 256, 0, stream>>>(src2, dst2, cursor, ssrc, E2);
    gstart_k<<<(N + 255) / 256, 256, 0, stream>>>(batch, gstart, N);

    const short* hin[NLAYER]     = {x_bf, hA_bf, hB_bf};
    const float* prevf[NLAYER]   = {nullptr, x, nullptr};
    const short* prevbf[NLAYER]  = {nullptr, nullptr, hA_bf};
    short* houtl[NLAYER]         = {hA_bf, hB_bf, x_bf};

    for (int l = 0; l < NLAYER; l++) {
        gemm_mfma<<<MTpad * 9, 256, 0, stream>>>(hin[l], Bt3 + (size_t)l * NP * KP,
                                                 xh_bf, asrc, adst, N, MT);
        aggregate<<<N, 256, 0, stream>>>(xh_bf, asrc, adst, off, ssrc, prevf[l], prevbf[l],
                                         b_att + l * FEAT, gamma + l * FEAT, beta + l * FEAT,
                                         r_mean + l * FEAT, r_var + l * FEAT,
                                         houtl[l], N);
        aggregate_tail<<<(N + 63) / 64, 256, 0, stream>>>(xh_bf, asrc, adst, off, ssrc,
                                         prevf[l], prevbf[l],
                                         b_att + l * FEAT, gamma + l * FEAT, beta + l * FEAT,
                                         r_mean + l * FEAT, r_var + l * FEAT,
                                         houtl[l], N);
    }

    pool_k<<<NGRAPH, 320, 0, stream>>>(x_bf, gstart, pooled);
    final_k<<<NGRAPH * 2, 64, 0, stream>>>(pooled, gstart, W_out, b_out, out);
}